// Round 3
// baseline (4003.316 us; speedup 1.0000x reference)
//
#include <hip/hip_runtime.h>

#define XB 65536  // 256*256

__device__ __forceinline__ float b2f(unsigned short s){
  unsigned u = ((unsigned)s) << 16;
  return __builtin_bit_cast(float, u);
}
__device__ __forceinline__ unsigned short f2b(float f){
  unsigned u = __builtin_bit_cast(unsigned, f);
  u = (u + 0x7FFFu + ((u >> 16) & 1u)) >> 16;
  return (unsigned short)u;
}
__device__ __forceinline__ float ldg_(const void* p, int i, int f32){
  return f32 ? ((const float*)p)[i] : b2f(((const unsigned short*)p)[i]);
}
__device__ __forceinline__ void stg_(void* p, int i, int f32, float v){
  if (f32) ((float*)p)[i] = v; else ((unsigned short*)p)[i] = f2b(v);
}

// -------- dtype detect: eps[0..3] = 0.6. f32 0.6f = 0x3F19999A ; bf16 pair = 0x3F1A3F1A --------
__global__ void kflag(const unsigned* __restrict__ eps, int* __restrict__ flag){
  flag[0] = (eps[0] == 0x3F19999Au) ? 1 : 0;
}

// -------- diag + adjacency bitfields --------
__global__ __launch_bounds__(256) void kprep(const void* __restrict__ x, float* __restrict__ diag,
                                             unsigned* __restrict__ xbits, const int* __restrict__ flagp){
  int dt = flagp[0];
  int b = blockIdx.x, n = threadIdx.x;
  int base = b * XB + n * 256;
  diag[b * 256 + n] = ldg_(x, b * XB + n * 257, dt);
  #pragma unroll
  for (int w = 0; w < 8; w++){
    unsigned bits = 0u;
    #pragma unroll
    for (int j = 0; j < 32; j++)
      if (ldg_(x, base + w * 32 + j, dt) > 0.5f) bits |= (1u << j);
    xbits[(b * 256 + n) * 8 + w] = bits;
  }
}

// -------- base[n][d] = sum_m x[n][m] * atom[m][d] --------
__global__ __launch_bounds__(256) void kgemm1(const void* __restrict__ x, const void* __restrict__ atom,
                                              void* __restrict__ baseB, const int* __restrict__ flagp, int ib1){
  int dt = flagp[0];
  __shared__ float As[64][17];
  __shared__ float Bs[16][65];
  int b = blockIdx.y;
  int tn = (blockIdx.x >> 2) * 64;
  int td = (blockIdx.x & 3) * 64;
  int tid = threadIdx.x, tx = tid & 15, ty = tid >> 4;
  float acc[4][4] = {};
  for (int k0 = 0; k0 < 256; k0 += 16){
    for (int t = tid; t < 1024; t += 256){
      int r = t >> 4, c = t & 15;
      As[r][c] = ldg_(x, b * XB + (tn + r) * 256 + k0 + c, dt);
    }
    for (int t = tid; t < 1024; t += 256){
      int r = t >> 6, c = t & 63;
      Bs[r][c] = ldg_(atom, b * XB + (k0 + r) * 256 + td + c, dt);
    }
    __syncthreads();
    #pragma unroll
    for (int kk = 0; kk < 16; kk++){
      float bv[4];
      #pragma unroll
      for (int j = 0; j < 4; j++) bv[j] = Bs[kk][tx * 4 + j];
      #pragma unroll
      for (int i = 0; i < 4; i++){
        float av = As[ty * 4 + i][kk];
        #pragma unroll
        for (int j = 0; j < 4; j++) acc[i][j] += av * bv[j];
      }
    }
    __syncthreads();
  }
  #pragma unroll
  for (int i = 0; i < 4; i++)
    #pragma unroll
    for (int j = 0; j < 4; j++)
      stg_(baseB, b * XB + (tn + ty * 4 + i) * 256 + td + tx * 4 + j, ib1, acc[i][j]);
}

// -------- h1[n][f] = lrelu( (base + (eps-1)*diag*atom) @ fcw + fcb ) --------
__global__ __launch_bounds__(256) void kgemm2(const void* __restrict__ baseB, const void* __restrict__ atom,
                                              const float* __restrict__ diag, const void* __restrict__ fcw,
                                              const void* __restrict__ fcb, const void* __restrict__ epsv, int h,
                                              void* __restrict__ h1, const int* __restrict__ flagp, int ib1){
  int dt = flagp[0];
  __shared__ float As[64][17];
  __shared__ float Bs[16][65];
  int b = blockIdx.y;
  int tn = (blockIdx.x >> 2) * 64;
  int tf = (blockIdx.x & 3) * 64;
  int tid = threadIdx.x, tx = tid & 15, ty = tid >> 4;
  float epsm1 = ldg_(epsv, h, dt) - 1.0f;
  float acc[4][4] = {};
  for (int k0 = 0; k0 < 256; k0 += 16){
    for (int t = tid; t < 1024; t += 256){
      int r = t >> 4, c = t & 15;
      int n = tn + r;
      float cj = epsm1 * diag[b * 256 + n];
      As[r][c] = ldg_(baseB, b * XB + n * 256 + k0 + c, ib1) + cj * ldg_(atom, b * XB + n * 256 + k0 + c, dt);
    }
    for (int t = tid; t < 1024; t += 256){
      int r = t >> 6, c = t & 63;
      Bs[r][c] = ldg_(fcw, (k0 + r) * 256 + tf + c, dt);
    }
    __syncthreads();
    #pragma unroll
    for (int kk = 0; kk < 16; kk++){
      float bv[4];
      #pragma unroll
      for (int j = 0; j < 4; j++) bv[j] = Bs[kk][tx * 4 + j];
      #pragma unroll
      for (int i = 0; i < 4; i++){
        float av = As[ty * 4 + i][kk];
        #pragma unroll
        for (int j = 0; j < 4; j++) acc[i][j] += av * bv[j];
      }
    }
    __syncthreads();
  }
  #pragma unroll
  for (int i = 0; i < 4; i++)
    #pragma unroll
    for (int j = 0; j < 4; j++){
      float t = acc[i][j] + ldg_(fcb, tf + tx * 4 + j, dt);
      t = t > 0.f ? t : 0.01f * t;
      stg_(h1, b * XB + (tn + ty * 4 + i) * 256 + tf + tx * 4 + j, ib1, t);
    }
}

// -------- feat[n][o] = h1 @ K_h + bias ; a_s/a_n deterministic reduce --------
__global__ __launch_bounds__(256) void kgemm3(const void* __restrict__ h1, const void* __restrict__ kers,
                                              const void* __restrict__ biases, const void* __restrict__ atts,
                                              const void* __restrict__ attn, int h,
                                              void* __restrict__ featB, float* __restrict__ a_s, float* __restrict__ a_n,
                                              const int* __restrict__ flagp, int ib1, int ibf){
  int dt = flagp[0];
  __shared__ float As[64][17];
  __shared__ float Bs[16][257];
  __shared__ float reds[64][17];
  __shared__ float redn[64][17];
  int b = blockIdx.y;
  int tn = blockIdx.x * 64;
  int tid = threadIdx.x, tx = tid & 15, ty = tid >> 4;
  float acc[4][16] = {};
  for (int k0 = 0; k0 < 256; k0 += 16){
    for (int t = tid; t < 1024; t += 256){
      int r = t >> 4, c = t & 15;
      As[r][c] = ldg_(h1, b * XB + (tn + r) * 256 + k0 + c, ib1);
    }
    for (int t = tid; t < 4096; t += 256){
      int r = t >> 8, c = t & 255;
      Bs[r][c] = ldg_(kers, h * XB + (k0 + r) * 256 + c, dt);
    }
    __syncthreads();
    #pragma unroll
    for (int kk = 0; kk < 16; kk++){
      float av[4];
      #pragma unroll
      for (int i = 0; i < 4; i++) av[i] = As[ty * 4 + i][kk];
      #pragma unroll
      for (int j = 0; j < 16; j++){
        float bv = Bs[kk][tx * 16 + j];
        #pragma unroll
        for (int i = 0; i < 4; i++) acc[i][j] += av[i] * bv;
      }
    }
    __syncthreads();
  }
  float ps[4] = {0.f,0.f,0.f,0.f}, pn[4] = {0.f,0.f,0.f,0.f};
  #pragma unroll
  for (int j = 0; j < 16; j++){
    int o = tx * 16 + j;
    float bias = ldg_(biases, h * 256 + o, dt);
    float ws_ = ldg_(atts, h * 256 + o, dt);
    float wn_ = ldg_(attn, h * 256 + o, dt);
    #pragma unroll
    for (int i = 0; i < 4; i++){
      float fv = acc[i][j] + bias;
      stg_(featB, b * XB + (tn + ty * 4 + i) * 256 + o, ibf, fv);
      ps[i] += fv * ws_;
      pn[i] += fv * wn_;
    }
  }
  #pragma unroll
  for (int i = 0; i < 4; i++){ reds[ty * 4 + i][tx] = ps[i]; redn[ty * 4 + i][tx] = pn[i]; }
  __syncthreads();
  if (tid < 64){
    float s = 0.f, nn = 0.f;
    #pragma unroll
    for (int t = 0; t < 16; t++){ s += reds[tid][t]; nn += redn[tid][t]; }
    a_s[b * 256 + tn + tid] = s;
    a_n[b * 256 + tn + tid] = nn;
  }
}

// -------- softmax(elu(a_s+a_n)+mask) ; out = P @ feat ; att[-1] dump for h==3 --------
__global__ __launch_bounds__(256) void kattn4(const unsigned* __restrict__ xbits,
                                              const float* __restrict__ a_s, const float* __restrict__ a_n,
                                              const void* __restrict__ attb, int h,
                                              const void* __restrict__ featB, void* __restrict__ out,
                                              const int* __restrict__ flagp, int ibf){
  int dt = flagp[0];
  __shared__ float P[32][257];
  __shared__ float Fs[16][257];
  int b = blockIdx.y, i0 = blockIdx.x * 32;
  int tid = threadIdx.x;

  // phase A: logits + softmax
  int row = tid >> 3, seg = tid & 7;
  int i = i0 + row;
  float asv = a_s[b * 256 + i] + ldg_(attb, h, dt);
  unsigned bits = xbits[(b * 256 + i) * 8 + seg];
  float Lv[32];
  float mx = -3.0e38f;
  #pragma unroll
  for (int e = 0; e < 32; e++){
    float an = a_n[b * 256 + seg * 32 + e];
    float s = asv + an;
    float el = s > 0.f ? s : (__expf(s) - 1.0f);
    float L = el + (((bits >> e) & 1u) ? 0.f : -1.0e10f);
    Lv[e] = L;
    mx = fmaxf(mx, L);
  }
  mx = fmaxf(mx, __shfl_xor(mx, 1));
  mx = fmaxf(mx, __shfl_xor(mx, 2));
  mx = fmaxf(mx, __shfl_xor(mx, 4));
  float sum = 0.f;
  #pragma unroll
  for (int e = 0; e < 32; e++){ float p = __expf(Lv[e] - mx); Lv[e] = p; sum += p; }
  sum += __shfl_xor(sum, 1);
  sum += __shfl_xor(sum, 2);
  sum += __shfl_xor(sum, 4);
  float inv = 1.0f / sum;
  #pragma unroll
  for (int e = 0; e < 32; e++){
    float p = Lv[e] * inv;
    P[row][seg * 32 + e] = p;
    if (h == 3){
      int oi = 33554432 + b * XB + i * 256 + seg * 32 + e;
      if (dt) ((float*)out)[oi] = p; else ((unsigned short*)out)[oi] = f2b(p);
    }
  }
  __syncthreads();

  // phase B: out rows = P @ feat
  int tx = tid & 15, ty = tid >> 4;
  float acc[2][16] = {};
  for (int j0 = 0; j0 < 256; j0 += 16){
    for (int t = tid; t < 4096; t += 256){
      int r = t >> 8, c = t & 255;
      Fs[r][c] = ldg_(featB, b * XB + (j0 + r) * 256 + c, ibf);
    }
    __syncthreads();
    #pragma unroll
    for (int jj = 0; jj < 16; jj++){
      float pv0 = P[ty * 2 + 0][j0 + jj];
      float pv1 = P[ty * 2 + 1][j0 + jj];
      #pragma unroll
      for (int c = 0; c < 16; c++){
        float fv = Fs[jj][tx * 16 + c];
        acc[0][c] += pv0 * fv;
        acc[1][c] += pv1 * fv;
      }
    }
    __syncthreads();
  }
  #pragma unroll
  for (int r = 0; r < 2; r++){
    int iw = i0 + ty * 2 + r;
    #pragma unroll
    for (int c = 0; c < 16; c++){
      int o = tx * 16 + c;
      int oi = (b * 256 + iw) * 1024 + h * 256 + o;
      if (dt) ((float*)out)[oi] = acc[r][c]; else ((unsigned short*)out)[oi] = f2b(acc[r][c]);
    }
  }
}

extern "C" void kernel_launch(void* const* d_in, const int* in_sizes, int n_in,
                              void* d_out, int out_size, void* d_ws, size_t ws_size,
                              hipStream_t stream) {
  const void* atom  = d_in[0];
  const void* x     = d_in[1];
  const void* fcw   = d_in[2];
  const void* fcb   = d_in[3];
  const void* kers  = d_in[4];
  const void* atts  = d_in[5];
  const void* attn  = d_in[6];
  const void* epsv  = d_in[7];
  const void* biases= d_in[8];
  const void* attb  = d_in[9];

  // intermediate precision chosen by available ws
  int ib1, ibf;
  if (ws_size >= (size_t)104 * 1024 * 1024){ ib1 = 1; ibf = 1; }
  else if (ws_size >= (size_t)70 * 1024 * 1024){ ib1 = 0; ibf = 1; }
  else { ib1 = 0; ibf = 0; }
  size_t Sb = ib1 ? 33554432u : 16777216u;
  size_t Sf = ibf ? 33554432u : 16777216u;

  char* w = (char*)d_ws;
  void* baseB = (void*)(w);
  void* h1    = (void*)(w + Sb);
  void* featB = (void*)(w + 2 * Sb);
  float* diag = (float*)(w + 2 * Sb + Sf);
  float* a_s  = (float*)(w + 2 * Sb + Sf + 131072);
  float* a_n  = (float*)(w + 2 * Sb + Sf + 262144);
  unsigned* xbits = (unsigned*)(w + 2 * Sb + Sf + 393216);
  int* flagp = (int*)(w + 2 * Sb + Sf + 393216 + 1048576);

  kflag<<<1, 1, 0, stream>>>((const unsigned*)epsv, flagp);
  kprep<<<128, 256, 0, stream>>>(x, diag, xbits, flagp);
  kgemm1<<<dim3(16, 128), 256, 0, stream>>>(x, atom, baseB, flagp, ib1);
  for (int h = 0; h < 4; ++h){
    kgemm2<<<dim3(16, 128), 256, 0, stream>>>(baseB, atom, diag, fcw, fcb, epsv, h, h1, flagp, ib1);
    kgemm3<<<dim3(4, 128), 256, 0, stream>>>(h1, kers, biases, atts, attn, h, featB, a_s, a_n, flagp, ib1, ibf);
    kattn4<<<dim3(8, 128), 256, 0, stream>>>(xbits, a_s, a_n, attb, h, featB, d_out, flagp, ibf);
  }
}

// Round 4
// 340.263 us; speedup vs baseline: 11.7654x; 11.7654x over previous
//
#include <hip/hip_runtime.h>

typedef __attribute__((ext_vector_type(8))) short bf16x8;
typedef __attribute__((ext_vector_type(4))) short short4v;
typedef __attribute__((ext_vector_type(4))) float f32x4;

// B=128, N=256, D=256, H=4 ; all matrices [256][256] per batch (65536 elems)

__device__ __forceinline__ float b2f(short s){
  unsigned u = ((unsigned)(unsigned short)s) << 16;
  return __builtin_bit_cast(float, u);
}
__device__ __forceinline__ short f2b(float f){
  unsigned u = __builtin_bit_cast(unsigned, f);
  u = (u + 0x7FFFu + ((u >> 16) & 1u)) >> 16;
  return (short)(unsigned short)u;
}

// ---------------- atom f32 -> bf16 (same layout) ----------------
__global__ __launch_bounds__(256) void kconvA(const float* __restrict__ in, short* __restrict__ out){
  int t = blockIdx.x * 256 + threadIdx.x;
  const f32x4* src = (const f32x4*)in;
  bf16x8* dst = (bf16x8*)out;
  #pragma unroll
  for (int half = 0; half < 2; half++){
    f32x4 a = src[t*4 + half*2], b = src[t*4 + half*2 + 1];
    bf16x8 o;
    #pragma unroll
    for (int e = 0; e < 4; e++){ o[e] = f2b(a[e]); o[4+e] = f2b(b[e]); }
    dst[t*2 + half] = o;
  }
}

// -------- x f32 -> bf16 + adjacency bitfields + diag -- grid (8,128), block 256 --------
__global__ __launch_bounds__(256) void kconvX(const float* __restrict__ x, short* __restrict__ xbf,
                                              unsigned* __restrict__ xbits, float* __restrict__ diag){
  int b = blockIdx.y;
  int row = blockIdx.x * 32 + (threadIdx.x >> 3);
  int seg = threadIdx.x & 7;
  const float* p = x + b*65536 + row*256 + seg*32;
  float v[32];
  #pragma unroll
  for (int k = 0; k < 8; k++){
    f32x4 q = ((const f32x4*)p)[k];
    #pragma unroll
    for (int e = 0; e < 4; e++) v[k*4+e] = q[e];
  }
  unsigned bits = 0u;
  #pragma unroll
  for (int e = 0; e < 32; e++) if (v[e] > 0.5f) bits |= (1u << e);
  xbits[(b*256 + row)*8 + seg] = bits;
  short* q = xbf + b*65536 + row*256 + seg*32;
  #pragma unroll
  for (int k = 0; k < 4; k++){
    bf16x8 o;
    #pragma unroll
    for (int e = 0; e < 8; e++) o[e] = f2b(v[k*8+e]);
    ((bf16x8*)q)[k] = o;
  }
  if ((row >> 5) == seg) diag[b*256 + row] = v[row & 31];
}

// -------- transpose-convert f32 [256][256] -> bf16 ^T : z=0 fc_w->WT, z=1..4 kernels->KhT --------
__global__ __launch_bounds__(256) void ktrans(const float* __restrict__ fcw, const float* __restrict__ kers,
                                              short* __restrict__ WT, short* __restrict__ KhT){
  __shared__ float tile[32][33];
  int z = blockIdx.z;
  const float* src = (z == 0) ? fcw : (kers + (z-1)*65536);
  short* dst = (z == 0) ? WT : (KhT + (z-1)*65536);
  int x0 = blockIdx.x*32, y0 = blockIdx.y*32;
  int tx = threadIdx.x & 31, ty = threadIdx.x >> 5;
  #pragma unroll
  for (int i = 0; i < 32; i += 8) tile[ty+i][tx] = src[(y0+ty+i)*256 + x0+tx];
  __syncthreads();
  #pragma unroll
  for (int i = 0; i < 32; i += 8) dst[(x0+ty+i)*256 + y0+tx] = f2b(tile[tx][ty+i]);
}

// -------- G2 = atom @ W : G2T[f][m] (scalar store) + G2nf[m][f] (vector C^T store) --------
// P(WT, atom): A rows f (k=d), B rows m (k=d). grid (4,128)
__global__ __launch_bounds__(256) void kG2(const short* __restrict__ WT, const short* __restrict__ atomb,
                                           short* __restrict__ G2T, short* __restrict__ G2nf){
  int b = blockIdx.y;
  int tr = (blockIdx.x >> 1) * 128, tc = (blockIdx.x & 1) * 128;
  int lane = threadIdx.x & 63, wave = threadIdx.x >> 6;
  int wr = (wave >> 1) * 64, wc = (wave & 1) * 64;
  const short* Y = atomb + b * 65536;
  int r0 = tr + wr + (lane & 15);
  int c0 = tc + wc + (lane & 15);
  int koff = (lane >> 4) * 8;
  f32x4 acc[4][4] = {};
  for (int k0 = 0; k0 < 256; k0 += 32){
    bf16x8 af[4], bfr[4];
    #pragma unroll
    for (int i = 0; i < 4; i++) af[i]  = *(const bf16x8*)(WT + (r0 + i*16)*256 + k0 + koff);
    #pragma unroll
    for (int j = 0; j < 4; j++) bfr[j] = *(const bf16x8*)(Y  + (c0 + j*16)*256 + k0 + koff);
    #pragma unroll
    for (int i = 0; i < 4; i++)
      #pragma unroll
      for (int j = 0; j < 4; j++)
        acc[i][j] = __builtin_amdgcn_mfma_f32_16x16x32_bf16(af[i], bfr[j], acc[i][j], 0, 0, 0);
  }
  int fi0 = tr + wr + (lane >> 4) * 4;   // D-row (f)
  int mj0 = tc + wc + (lane & 15);       // D-col (m)
  #pragma unroll
  for (int i = 0; i < 4; i++)
    #pragma unroll
    for (int j = 0; j < 4; j++){
      short4v v;
      #pragma unroll
      for (int r = 0; r < 4; r++) v[r] = f2b(acc[i][j][r]);
      *(short4v*)(G2nf + b*65536 + (mj0 + j*16)*256 + fi0 + i*16) = v;   // [m][f] vector
      #pragma unroll
      for (int r = 0; r < 4; r++)
        G2T[b*65536 + (fi0 + i*16 + r)*256 + mj0 + j*16] = v[r];         // [f][m] scalar
    }
}

// -------- G1 = x @ G2 : P(G2T, xbf), C^T store G1[n][f] --------
__global__ __launch_bounds__(256) void kG1(const short* __restrict__ G2T, const short* __restrict__ xbf,
                                           short* __restrict__ G1){
  int b = blockIdx.y;
  int tr = (blockIdx.x >> 1) * 128, tc = (blockIdx.x & 1) * 128;
  int lane = threadIdx.x & 63, wave = threadIdx.x >> 6;
  int wr = (wave >> 1) * 64, wc = (wave & 1) * 64;
  const short* X = G2T + b * 65536;  // rows f, k=m
  const short* Y = xbf + b * 65536;  // rows n, k=m
  int r0 = tr + wr + (lane & 15);
  int c0 = tc + wc + (lane & 15);
  int koff = (lane >> 4) * 8;
  f32x4 acc[4][4] = {};
  for (int k0 = 0; k0 < 256; k0 += 32){
    bf16x8 af[4], bfr[4];
    #pragma unroll
    for (int i = 0; i < 4; i++) af[i]  = *(const bf16x8*)(X + (r0 + i*16)*256 + k0 + koff);
    #pragma unroll
    for (int j = 0; j < 4; j++) bfr[j] = *(const bf16x8*)(Y + (c0 + j*16)*256 + k0 + koff);
    #pragma unroll
    for (int i = 0; i < 4; i++)
      #pragma unroll
      for (int j = 0; j < 4; j++)
        acc[i][j] = __builtin_amdgcn_mfma_f32_16x16x32_bf16(af[i], bfr[j], acc[i][j], 0, 0, 0);
  }
  int fi0 = tr + wr + (lane >> 4) * 4;   // f
  int nj0 = tc + wc + (lane & 15);       // n
  #pragma unroll
  for (int i = 0; i < 4; i++)
    #pragma unroll
    for (int j = 0; j < 4; j++){
      short4v v;
      #pragma unroll
      for (int r = 0; r < 4; r++) v[r] = f2b(acc[i][j][r]);
      *(short4v*)(G1 + b*65536 + (nj0 + j*16)*256 + fi0 + i*16) = v;     // [n][f]
    }
}

// -------- featT_h[o][n] = (h1_h @ K_h + bias)^T ; h1 rebuilt on the fly; a_s/a_n reduce --------
// P(KhT_h, h1): A rows o (k=f), B rows n (k=f). Block: 4 waves x 64 o-rows, 64 n cols. grid (4,128)
__global__ __launch_bounds__(256) void kFeat(const short* __restrict__ KhT, const short* __restrict__ G1,
                                             const short* __restrict__ G2nf, const float* __restrict__ diag,
                                             const float* __restrict__ fcb, const float* __restrict__ epsv, int h,
                                             const float* __restrict__ biases, const float* __restrict__ atts,
                                             const float* __restrict__ attn,
                                             short* __restrict__ featT, float* __restrict__ a_s, float* __restrict__ a_n){
  __shared__ float red_s[4][64];
  __shared__ float red_n[4][64];
  int b = blockIdx.y;
  int tc = blockIdx.x * 64;
  int tid = threadIdx.x, lane = tid & 63, w = tid >> 6;
  float epsm1 = epsv[h] - 1.0f;
  const short* KA = KhT + h * 65536;
  const short* G1b = G1 + b * 65536;
  const short* G2b = G2nf + b * 65536;
  int or0 = w*64 + (lane & 15);
  int nn0 = tc + (lane & 15);
  int koff = (lane >> 4) * 8;
  float cj[4];
  #pragma unroll
  for (int j = 0; j < 4; j++) cj[j] = epsm1 * diag[b*256 + nn0 + j*16];
  f32x4 acc[4][4] = {};
  for (int k0 = 0; k0 < 256; k0 += 32){
    float fb[8];
    {
      f32x4 f0 = *(const f32x4*)(fcb + k0 + koff);
      f32x4 f1 = *(const f32x4*)(fcb + k0 + koff + 4);
      #pragma unroll
      for (int e = 0; e < 4; e++){ fb[e] = f0[e]; fb[4+e] = f1[e]; }
    }
    bf16x8 af[4], hb[4];
    #pragma unroll
    for (int i = 0; i < 4; i++) af[i] = *(const bf16x8*)(KA + (or0 + i*16)*256 + k0 + koff);
    #pragma unroll
    for (int j = 0; j < 4; j++){
      bf16x8 g1 = *(const bf16x8*)(G1b + (nn0 + j*16)*256 + k0 + koff);
      bf16x8 g2 = *(const bf16x8*)(G2b + (nn0 + j*16)*256 + k0 + koff);
      bf16x8 o;
      #pragma unroll
      for (int e = 0; e < 8; e++){
        float v = b2f(g1[e]) + cj[j]*b2f(g2[e]) + fb[e];
        v = v > 0.f ? v : 0.01f*v;
        o[e] = f2b(v);
      }
      hb[j] = o;
    }
    #pragma unroll
    for (int i = 0; i < 4; i++)
      #pragma unroll
      for (int j = 0; j < 4; j++)
        acc[i][j] = __builtin_amdgcn_mfma_f32_16x16x32_bf16(af[i], hb[j], acc[i][j], 0, 0, 0);
  }
  int oo0 = w*64 + (lane >> 4) * 4;
  float ps[4] = {0.f,0.f,0.f,0.f}, pn[4] = {0.f,0.f,0.f,0.f};
  #pragma unroll
  for (int i = 0; i < 4; i++){
    #pragma unroll
    for (int r = 0; r < 4; r++){
      int o = oo0 + i*16 + r;
      float bias = biases[h*256 + o];
      float ws_ = atts[h*256 + o];
      float wn_ = attn[h*256 + o];
      #pragma unroll
      for (int j = 0; j < 4; j++){
        float fv = acc[i][j][r] + bias;
        featT[b*65536 + o*256 + nn0 + j*16] = f2b(fv);
        ps[j] += fv * ws_;
        pn[j] += fv * wn_;
      }
    }
  }
  #pragma unroll
  for (int j = 0; j < 4; j++){
    float s = ps[j]; s += __shfl_xor(s, 16); s += __shfl_xor(s, 32);
    float nv = pn[j]; nv += __shfl_xor(nv, 16); nv += __shfl_xor(nv, 32);
    if (lane < 16){
      red_s[w][j*16 + lane] = s;
      red_n[w][j*16 + lane] = nv;
    }
  }
  __syncthreads();
  if (tid < 64){
    float ss = red_s[0][tid] + red_s[1][tid] + red_s[2][tid] + red_s[3][tid];
    float nn = red_n[0][tid] + red_n[1][tid] + red_n[2][tid] + red_n[3][tid];
    a_s[b*256 + tc + tid] = ss;
    a_n[b*256 + tc + tid] = nn;
  }
}

// -------- softmax(elu(a_s+a_n)+mask) ; node = P @ feat ; f32 out ; att dump for h==3 --------
__global__ __launch_bounds__(256) void kAttn(const unsigned* __restrict__ xbits,
                                             const float* __restrict__ a_s, const float* __restrict__ a_n,
                                             const float* __restrict__ attbv, int h,
                                             const short* __restrict__ featT,
                                             float* __restrict__ out, float* __restrict__ out2){
  __shared__ __align__(16) short Pbuf[32][264];
  int b = blockIdx.y, it0 = blockIdx.x * 32;
  int tid = threadIdx.x, lane = tid & 63, w = tid >> 6;

  // phase A: 32 rows x (8 segs x 32 cols)
  int row = tid >> 3, seg = tid & 7;
  int i = it0 + row;
  float asv = a_s[b*256 + i] + attbv[h];
  unsigned bits = xbits[(b*256 + i)*8 + seg];
  const f32x4* an4 = (const f32x4*)(a_n + b*256 + seg*32);
  float Lv[32];
  float mx = -3.0e38f;
  #pragma unroll
  for (int kk = 0; kk < 8; kk++){
    f32x4 a = an4[kk];
    #pragma unroll
    for (int e = 0; e < 4; e++){
      float s = asv + a[e];
      float el = s > 0.f ? s : (__expf(s) - 1.0f);
      float L = el + (((bits >> (kk*4+e)) & 1u) ? 0.f : -1.0e10f);
      Lv[kk*4+e] = L;
      mx = fmaxf(mx, L);
    }
  }
  mx = fmaxf(mx, __shfl_xor(mx, 1));
  mx = fmaxf(mx, __shfl_xor(mx, 2));
  mx = fmaxf(mx, __shfl_xor(mx, 4));
  float sum = 0.f;
  #pragma unroll
  for (int e = 0; e < 32; e++){ float p = __expf(Lv[e] - mx); Lv[e] = p; sum += p; }
  sum += __shfl_xor(sum, 1);
  sum += __shfl_xor(sum, 2);
  sum += __shfl_xor(sum, 4);
  float inv = 1.0f / sum;
  #pragma unroll
  for (int kk = 0; kk < 4; kk++){
    bf16x8 pv;
    #pragma unroll
    for (int e = 0; e < 8; e++) pv[e] = f2b(Lv[kk*8+e] * inv);
    *(bf16x8*)&Pbuf[row][seg*32 + kk*8] = pv;
  }
  if (h == 3){
    float* o2 = out2 + b*65536 + i*256 + seg*32;
    #pragma unroll
    for (int kk = 0; kk < 8; kk++){
      f32x4 v;
      #pragma unroll
      for (int e = 0; e < 4; e++) v[e] = Lv[kk*4+e] * inv;
      *(f32x4*)(o2 + kk*4) = v;
    }
  }
  __syncthreads();

  // phase B: nodeT = P(featT, Pbuf) ; C^T-write f32 to out
  int o0w = w * 64;
  const short* F = featT + b * 65536;
  int orow = o0w + (lane & 15);
  int koff = (lane >> 4) * 8;
  f32x4 acc[4][2] = {};
  for (int k0 = 0; k0 < 256; k0 += 32){
    bf16x8 af[4], bfr[2];
    #pragma unroll
    for (int ii = 0; ii < 4; ii++) af[ii] = *(const bf16x8*)(F + (orow + ii*16)*256 + k0 + koff);
    #pragma unroll
    for (int jf = 0; jf < 2; jf++) bfr[jf] = *(const bf16x8*)&Pbuf[jf*16 + (lane & 15)][k0 + koff];
    #pragma unroll
    for (int ii = 0; ii < 4; ii++)
      #pragma unroll
      for (int jf = 0; jf < 2; jf++)
        acc[ii][jf] = __builtin_amdgcn_mfma_f32_16x16x32_bf16(af[ii], bfr[jf], acc[ii][jf], 0, 0, 0);
  }
  int oo0 = o0w + (lane >> 4) * 4;
  #pragma unroll
  for (int ii = 0; ii < 4; ii++)
    #pragma unroll
    for (int jf = 0; jf < 2; jf++){
      int iW = it0 + jf*16 + (lane & 15);
      *(f32x4*)(out + (size_t)(b*256 + iW)*1024 + h*256 + oo0 + ii*16) = acc[ii][jf];
    }
}

extern "C" void kernel_launch(void* const* d_in, const int* in_sizes, int n_in,
                              void* d_out, int out_size, void* d_ws, size_t ws_size,
                              hipStream_t stream) {
  const float* atom   = (const float*)d_in[0];
  const float* x      = (const float*)d_in[1];
  const float* fc_w   = (const float*)d_in[2];
  const float* fc_b   = (const float*)d_in[3];
  const float* kers   = (const float*)d_in[4];
  const float* att_s  = (const float*)d_in[5];
  const float* att_n  = (const float*)d_in[6];
  const float* eps    = (const float*)d_in[7];
  const float* biases = (const float*)d_in[8];
  const float* att_b  = (const float*)d_in[9];

  // ws layout (69.2 MB total)
  char* w = (char*)d_ws;
  short* WT      = (short*)(w);                      // 128 KB
  short* KhT     = (short*)(w + 131072);             // 512 KB
  float* diag    = (float*)(w + 655360);             // 128 KB
  float* a_s     = (float*)(w + 786432);             // 128 KB
  float* a_n     = (float*)(w + 917504);             // 128 KB
  unsigned* xbits= (unsigned*)(w + 1048576);         // 1 MB
  short* atomG1  = (short*)(w + 2097152);            // 16 MB: atom_bf, then G1
  short* xbfFeat = (short*)(w + 18874368);           // 16 MB: x_bf, then featT
  short* G2T     = (short*)(w + 35651584);           // 16 MB
  short* G2nf    = (short*)(w + 52428800);           // 16 MB

  float* out  = (float*)d_out;
  float* out2 = out + 33554432;  // B*N*H*D floats

  ktrans<<<dim3(8, 8, 5), 256, 0, stream>>>(fc_w, kers, WT, KhT);
  kconvA<<<dim3(2048), 256, 0, stream>>>(atom, atomG1);
  kconvX<<<dim3(8, 128), 256, 0, stream>>>(x, xbfFeat, xbits, diag);
  kG2<<<dim3(4, 128), 256, 0, stream>>>(WT, atomG1, G2T, G2nf);
  kG1<<<dim3(4, 128), 256, 0, stream>>>(G2T, xbfFeat, atomG1);   // G1 overwrites atom_bf (dead)

  for (int h = 0; h < 4; ++h){
    kFeat<<<dim3(4, 128), 256, 0, stream>>>(KhT, atomG1, G2nf, diag, fc_b, eps, h,
                                            biases, att_s, att_n, xbfFeat, a_s, a_n); // featT overwrites x_bf (dead)
    kAttn<<<dim3(8, 128), 256, 0, stream>>>(xbits, a_s, a_n, att_b, h, xbfFeat, out, out2);
  }
}

// Round 5
// 315.217 us; speedup vs baseline: 12.7002x; 1.0795x over previous
//
#include <hip/hip_runtime.h>

typedef __attribute__((ext_vector_type(8))) short bf16x8;
typedef __attribute__((ext_vector_type(4))) short short4v;
typedef __attribute__((ext_vector_type(4))) float f32x4;

// B=128, N=256, D=256, H=4 ; per-batch matrices are [256][256] (65536 elems)

__device__ __forceinline__ float b2f(short s){
  unsigned u = ((unsigned)(unsigned short)s) << 16;
  return __builtin_bit_cast(float, u);
}
__device__ __forceinline__ short f2b(float f){
  unsigned u = __builtin_bit_cast(unsigned, f);
  u = (u + 0x7FFFu + ((u >> 16) & 1u)) >> 16;
  return (short)(unsigned short)u;
}

// -------- transpose-convert f32 [256][256] -> bf16 ^T : z=0 fc_w->WT, z=1..4 kernels->KhT --------
__global__ __launch_bounds__(256) void ktrans(const float* __restrict__ fcw, const float* __restrict__ kers,
                                              short* __restrict__ WT, short* __restrict__ KhT){
  __shared__ float tile[32][33];
  int z = blockIdx.z;
  const float* src = (z == 0) ? fcw : (kers + (z-1)*65536);
  short* dst = (z == 0) ? WT : (KhT + (z-1)*65536);
  int x0 = blockIdx.x*32, y0 = blockIdx.y*32;
  int tx = threadIdx.x & 31, ty = threadIdx.x >> 5;
  #pragma unroll
  for (int i = 0; i < 32; i += 8) tile[ty+i][tx] = src[(y0+ty+i)*256 + x0+tx];
  __syncthreads();
  #pragma unroll
  for (int i = 0; i < 32; i += 8) dst[(x0+ty+i)*256 + y0+tx] = f2b(tile[tx][ty+i]);
}

// -------- prep: z=0 atom f32->bf16 ; z=1 x f32->bf16 + bitfields + diag. grid (8,128,2) --------
__global__ __launch_bounds__(256) void kprep(const float* __restrict__ atom, const float* __restrict__ x,
                                             short* __restrict__ atom_bf, short* __restrict__ xbf,
                                             unsigned* __restrict__ xbits, float* __restrict__ diag){
  int b = blockIdx.y;
  int row = blockIdx.x*32 + (threadIdx.x >> 3);
  int seg = threadIdx.x & 7;
  if (blockIdx.z == 0){
    const float* p = atom + b*65536 + row*256 + seg*32;
    short* q = atom_bf + b*65536 + row*256 + seg*32;
    #pragma unroll
    for (int k = 0; k < 4; k++){
      f32x4 a = ((const f32x4*)p)[k*2], c = ((const f32x4*)p)[k*2+1];
      bf16x8 o;
      #pragma unroll
      for (int e = 0; e < 4; e++){ o[e] = f2b(a[e]); o[4+e] = f2b(c[e]); }
      ((bf16x8*)q)[k] = o;
    }
  } else {
    const float* p = x + b*65536 + row*256 + seg*32;
    float v[32];
    #pragma unroll
    for (int k = 0; k < 8; k++){
      f32x4 qv = ((const f32x4*)p)[k];
      #pragma unroll
      for (int e = 0; e < 4; e++) v[k*4+e] = qv[e];
    }
    unsigned bits = 0u;
    #pragma unroll
    for (int e = 0; e < 32; e++) if (v[e] > 0.5f) bits |= (1u << e);
    xbits[(b*256 + row)*8 + seg] = bits;
    short* q = xbf + b*65536 + row*256 + seg*32;
    #pragma unroll
    for (int k = 0; k < 4; k++){
      bf16x8 o;
      #pragma unroll
      for (int e = 0; e < 8; e++) o[e] = f2b(v[k*8+e]);
      ((bf16x8*)q)[k] = o;
    }
    if ((row >> 5) == seg) diag[b*256 + row] = v[row & 31];
  }
}

// -------- G2 = atom @ W : G2T[f][m] (scalar) + G2nf[m][f] (vector C^T). grid (4,128) --------
__global__ __launch_bounds__(256) void kG2(const short* __restrict__ WT, const short* __restrict__ atomb,
                                           short* __restrict__ G2T, short* __restrict__ G2nf){
  int b = blockIdx.y;
  int tr = (blockIdx.x >> 1) * 128, tc = (blockIdx.x & 1) * 128;
  int lane = threadIdx.x & 63, wave = threadIdx.x >> 6;
  int wr = (wave >> 1) * 64, wc = (wave & 1) * 64;
  const short* Y = atomb + b * 65536;
  int r0 = tr + wr + (lane & 15);
  int c0 = tc + wc + (lane & 15);
  int koff = (lane >> 4) * 8;
  f32x4 acc[4][4] = {};
  for (int k0 = 0; k0 < 256; k0 += 32){
    bf16x8 af[4], bfr[4];
    #pragma unroll
    for (int i = 0; i < 4; i++) af[i]  = *(const bf16x8*)(WT + (r0 + i*16)*256 + k0 + koff);
    #pragma unroll
    for (int j = 0; j < 4; j++) bfr[j] = *(const bf16x8*)(Y  + (c0 + j*16)*256 + k0 + koff);
    #pragma unroll
    for (int i = 0; i < 4; i++)
      #pragma unroll
      for (int j = 0; j < 4; j++)
        acc[i][j] = __builtin_amdgcn_mfma_f32_16x16x32_bf16(af[i], bfr[j], acc[i][j], 0, 0, 0);
  }
  int fi0 = tr + wr + (lane >> 4) * 4;
  int mj0 = tc + wc + (lane & 15);
  #pragma unroll
  for (int i = 0; i < 4; i++)
    #pragma unroll
    for (int j = 0; j < 4; j++){
      short4v v;
      #pragma unroll
      for (int r = 0; r < 4; r++) v[r] = f2b(acc[i][j][r]);
      *(short4v*)(G2nf + b*65536 + (mj0 + j*16)*256 + fi0 + i*16) = v;   // [m][f]
      #pragma unroll
      for (int r = 0; r < 4; r++)
        G2T[b*65536 + (fi0 + i*16 + r)*256 + mj0 + j*16] = v[r];         // [f][m]
    }
}

// -------- G1 = x @ G2 : P(G2T, xbf), C^T store G1[n][f]. grid (4,128) --------
__global__ __launch_bounds__(256) void kG1(const short* __restrict__ G2T, const short* __restrict__ xbf,
                                           short* __restrict__ G1){
  int b = blockIdx.y;
  int tr = (blockIdx.x >> 1) * 128, tc = (blockIdx.x & 1) * 128;
  int lane = threadIdx.x & 63, wave = threadIdx.x >> 6;
  int wr = (wave >> 1) * 64, wc = (wave & 1) * 64;
  const short* X = G2T + b * 65536;
  const short* Y = xbf + b * 65536;
  int r0 = tr + wr + (lane & 15);
  int c0 = tc + wc + (lane & 15);
  int koff = (lane >> 4) * 8;
  f32x4 acc[4][4] = {};
  for (int k0 = 0; k0 < 256; k0 += 32){
    bf16x8 af[4], bfr[4];
    #pragma unroll
    for (int i = 0; i < 4; i++) af[i]  = *(const bf16x8*)(X + (r0 + i*16)*256 + k0 + koff);
    #pragma unroll
    for (int j = 0; j < 4; j++) bfr[j] = *(const bf16x8*)(Y + (c0 + j*16)*256 + k0 + koff);
    #pragma unroll
    for (int i = 0; i < 4; i++)
      #pragma unroll
      for (int j = 0; j < 4; j++)
        acc[i][j] = __builtin_amdgcn_mfma_f32_16x16x32_bf16(af[i], bfr[j], acc[i][j], 0, 0, 0);
  }
  int fi0 = tr + wr + (lane >> 4) * 4;
  int nj0 = tc + wc + (lane & 15);
  #pragma unroll
  for (int i = 0; i < 4; i++)
    #pragma unroll
    for (int j = 0; j < 4; j++){
      short4v v;
      #pragma unroll
      for (int r = 0; r < 4; r++) v[r] = f2b(acc[i][j][r]);
      *(short4v*)(G1 + b*65536 + (nj0 + j*16)*256 + fi0 + i*16) = v;     // [n][f]
    }
}

// -------- featT_h[o][n] = (h1_h @ K_h + bias)^T, h1 rebuilt on the fly; a_s/a_n reduce --------
// grid (4,128,4) = (n-tile 64, b, h). Block: 2x2 wave grid, wave = 128 o x 32 n.
__global__ __launch_bounds__(256) void kFeatAll(const short* __restrict__ KhT, const short* __restrict__ G1,
                                                const short* __restrict__ G2nf, const float* __restrict__ diag,
                                                const float* __restrict__ fcb, const float* __restrict__ epsv,
                                                const float* __restrict__ biases, const float* __restrict__ atts,
                                                const float* __restrict__ attn,
                                                short* __restrict__ fT0, short* __restrict__ fT1,
                                                short* __restrict__ fT2, short* __restrict__ fT3,
                                                float* __restrict__ a_s, float* __restrict__ a_n){
  __shared__ float red_s[4][32];
  __shared__ float red_n[4][32];
  int h = blockIdx.z, b = blockIdx.y;
  int tc = blockIdx.x * 64;
  int tid = threadIdx.x, lane = tid & 63, w = tid >> 6;
  short* featT = (h==0)?fT0:(h==1)?fT1:(h==2)?fT2:fT3;
  float epsm1 = epsv[h] - 1.0f;
  const short* KA = KhT + h*65536;
  const short* G1b = G1 + b*65536;
  const short* G2b = G2nf + b*65536;
  int wro = (w >> 1) * 128, wcn = (w & 1) * 32;
  int lr = lane & 15, lq = lane >> 4;
  int koff = lq * 8;
  int nj[2]; float cj[2];
  #pragma unroll
  for (int j = 0; j < 2; j++){
    nj[j] = tc + wcn + j*16 + lr;
    cj[j] = epsm1 * diag[b*256 + nj[j]];
  }
  f32x4 acc[8][2] = {};
  for (int k0 = 0; k0 < 256; k0 += 32){
    f32x4 f0 = *(const f32x4*)(fcb + k0 + koff);
    f32x4 f1 = *(const f32x4*)(fcb + k0 + koff + 4);
    bf16x8 hb[2];
    #pragma unroll
    for (int j = 0; j < 2; j++){
      bf16x8 g1 = *(const bf16x8*)(G1b + nj[j]*256 + k0 + koff);
      bf16x8 g2 = *(const bf16x8*)(G2b + nj[j]*256 + k0 + koff);
      bf16x8 o;
      #pragma unroll
      for (int e = 0; e < 8; e++){
        float fb = (e < 4) ? f0[e] : f1[e-4];
        float v = b2f(g1[e]) + cj[j]*b2f(g2[e]) + fb;
        v = v > 0.f ? v : 0.01f*v;
        o[e] = f2b(v);
      }
      hb[j] = o;
    }
    #pragma unroll
    for (int i = 0; i < 8; i++){
      bf16x8 af = *(const bf16x8*)(KA + (wro + i*16 + lr)*256 + k0 + koff);
      acc[i][0] = __builtin_amdgcn_mfma_f32_16x16x32_bf16(af, hb[0], acc[i][0], 0, 0, 0);
      acc[i][1] = __builtin_amdgcn_mfma_f32_16x16x32_bf16(af, hb[1], acc[i][1], 0, 0, 0);
    }
  }
  int c4 = lq * 4;
  float ps[2] = {0.f, 0.f}, pn[2] = {0.f, 0.f};
  #pragma unroll
  for (int i = 0; i < 8; i++){
    int ob = wro + i*16 + c4;
    f32x4 bi  = *(const f32x4*)(biases + h*256 + ob);
    f32x4 ws4 = *(const f32x4*)(atts   + h*256 + ob);
    f32x4 wn4 = *(const f32x4*)(attn   + h*256 + ob);
    #pragma unroll
    for (int r = 0; r < 4; r++){
      #pragma unroll
      for (int j = 0; j < 2; j++){
        float fv = acc[i][j][r] + bi[r];
        featT[b*65536 + (ob + r)*256 + nj[j]] = f2b(fv);
        ps[j] += fv * ws4[r];
        pn[j] += fv * wn4[r];
      }
    }
  }
  #pragma unroll
  for (int j = 0; j < 2; j++){
    float s = ps[j]; s += __shfl_xor(s, 16); s += __shfl_xor(s, 32);
    float nv = pn[j]; nv += __shfl_xor(nv, 16); nv += __shfl_xor(nv, 32);
    if (lane < 16){
      red_s[w][wcn/32*0 + j*16 + lane] = s;   // local n-in-32 index
      red_n[w][j*16 + lane] = nv;
      red_s[w][j*16 + lane] = s;
    }
  }
  __syncthreads();
  if (tid < 64){
    int g = tid >> 5;       // 0: waves {0,2} (wcn=0) ; 1: waves {1,3} (wcn=32)
    int idx = tid & 31;
    float ss = red_s[g][idx] + red_s[g+2][idx];
    float nn = red_n[g][idx] + red_n[g+2][idx];
    a_s[(h*128 + b)*256 + tc + tid] = ss;
    a_n[(h*128 + b)*256 + tc + tid] = nn;
  }
}

// -------- softmax(elu(a_s+a_n)+mask) ; node = P @ feat ; f32 out ; att dump h==3 --------
// grid (8,128,4) = (i-tile 32, b, h)
__global__ __launch_bounds__(256) void kAttnAll(const unsigned* __restrict__ xbits,
                                                const float* __restrict__ a_s, const float* __restrict__ a_n,
                                                const float* __restrict__ attbv,
                                                const short* __restrict__ fT0, const short* __restrict__ fT1,
                                                const short* __restrict__ fT2, const short* __restrict__ fT3,
                                                float* __restrict__ out, float* __restrict__ out2){
  __shared__ __align__(16) short Pbuf[32][264];
  int h = blockIdx.z, b = blockIdx.y, it0 = blockIdx.x * 32;
  int tid = threadIdx.x, lane = tid & 63, w = tid >> 6;
  const short* featT = (h==0)?fT0:(h==1)?fT1:(h==2)?fT2:fT3;
  const float* asp = a_s + (h*128 + b)*256;
  const float* anp = a_n + (h*128 + b)*256;

  // phase A: 32 rows x (8 segs x 32 cols)
  int row = tid >> 3, seg = tid & 7;
  int i = it0 + row;
  float asv = asp[i] + attbv[h];
  unsigned bits = xbits[(b*256 + i)*8 + seg];
  const f32x4* an4 = (const f32x4*)(anp + seg*32);
  float Lv[32];
  float mx = -3.0e38f;
  #pragma unroll
  for (int kk = 0; kk < 8; kk++){
    f32x4 a = an4[kk];
    #pragma unroll
    for (int e = 0; e < 4; e++){
      float s = asv + a[e];
      float el = s > 0.f ? s : (__expf(s) - 1.0f);
      float L = el + (((bits >> (kk*4+e)) & 1u) ? 0.f : -1.0e10f);
      Lv[kk*4+e] = L;
      mx = fmaxf(mx, L);
    }
  }
  mx = fmaxf(mx, __shfl_xor(mx, 1));
  mx = fmaxf(mx, __shfl_xor(mx, 2));
  mx = fmaxf(mx, __shfl_xor(mx, 4));
  float sum = 0.f;
  #pragma unroll
  for (int e = 0; e < 32; e++){ float p = __expf(Lv[e] - mx); Lv[e] = p; sum += p; }
  sum += __shfl_xor(sum, 1);
  sum += __shfl_xor(sum, 2);
  sum += __shfl_xor(sum, 4);
  float inv = 1.0f / sum;
  #pragma unroll
  for (int kk = 0; kk < 4; kk++){
    bf16x8 pv;
    #pragma unroll
    for (int e = 0; e < 8; e++) pv[e] = f2b(Lv[kk*8+e] * inv);
    *(bf16x8*)&Pbuf[row][seg*32 + kk*8] = pv;
  }
  if (h == 3){
    float* o2 = out2 + b*65536 + i*256 + seg*32;
    #pragma unroll
    for (int kk = 0; kk < 8; kk++){
      f32x4 v;
      #pragma unroll
      for (int e = 0; e < 4; e++) v[e] = Lv[kk*4+e] * inv;
      *(f32x4*)(o2 + kk*4) = v;
    }
  }
  __syncthreads();

  // phase B: nodeT = P(featT, Pbuf) ; C^T-write f32 to out
  int o0w = w * 64;
  const short* F = featT + b * 65536;
  int orow = o0w + (lane & 15);
  int koff = (lane >> 4) * 8;
  f32x4 acc[4][2] = {};
  for (int k0 = 0; k0 < 256; k0 += 32){
    bf16x8 af[4], bfr[2];
    #pragma unroll
    for (int ii = 0; ii < 4; ii++) af[ii] = *(const bf16x8*)(F + (orow + ii*16)*256 + k0 + koff);
    #pragma unroll
    for (int jf = 0; jf < 2; jf++) bfr[jf] = *(const bf16x8*)&Pbuf[jf*16 + (lane & 15)][k0 + koff];
    #pragma unroll
    for (int ii = 0; ii < 4; ii++)
      #pragma unroll
      for (int jf = 0; jf < 2; jf++)
        acc[ii][jf] = __builtin_amdgcn_mfma_f32_16x16x32_bf16(af[ii], bfr[jf], acc[ii][jf], 0, 0, 0);
  }
  int oo0 = o0w + (lane >> 4) * 4;
  #pragma unroll
  for (int ii = 0; ii < 4; ii++)
    #pragma unroll
    for (int jf = 0; jf < 2; jf++){
      int iW = it0 + jf*16 + (lane & 15);
      *(f32x4*)(out + (size_t)(b*256 + iW)*1024 + h*256 + oo0 + ii*16) = acc[ii][jf];
    }
}

extern "C" void kernel_launch(void* const* d_in, const int* in_sizes, int n_in,
                              void* d_out, int out_size, void* d_ws, size_t ws_size,
                              hipStream_t stream) {
  const float* atom   = (const float*)d_in[0];
  const float* x      = (const float*)d_in[1];
  const float* fc_w   = (const float*)d_in[2];
  const float* fc_b   = (const float*)d_in[3];
  const float* kers   = (const float*)d_in[4];
  const float* att_s  = (const float*)d_in[5];
  const float* att_n  = (const float*)d_in[6];
  const float* eps    = (const float*)d_in[7];
  const float* biases = (const float*)d_in[8];
  const float* att_b  = (const float*)d_in[9];

  // ws layout, 98.8 MiB total (ws_size >= 104 MiB established in R3).
  char* w = (char*)d_ws;
  short* WT      = (short*)(w);                      // 128 KB
  short* KhT     = (short*)(w + 131072);             // 512 KB
  float* diag    = (float*)(w + 655360);             // 128 KB
  float* a_s     = (float*)(w + 786432);             // 512 KB  [h][b][n]
  float* a_n     = (float*)(w + 1310720);            // 512 KB
  unsigned* xbits= (unsigned*)(w + 1835008);         // 1 MB
  short* atomG1  = (short*)(w + 2883584);            // 16 MB: atom_bf, then G1
  short* xbfF0   = (short*)(w + 19660800);           // 16 MB: x_bf, then featT[0]
  short* G2TF1   = (short*)(w + 36438016);           // 16 MB: G2T, then featT[1]
  short* G2nf    = (short*)(w + 53215232);           // 16 MB
  short* fT2     = (short*)(w + 69992448);           // 16 MB
  short* fT3     = (short*)(w + 86769664);           // 16 MB

  float* out  = (float*)d_out;
  float* out2 = out + 33554432;  // B*N*H*D floats

  ktrans<<<dim3(8, 8, 5), 256, 0, stream>>>(fc_w, kers, WT, KhT);
  kprep<<<dim3(8, 128, 2), 256, 0, stream>>>(atom, x, atomG1, xbfF0, xbits, diag);
  kG2<<<dim3(4, 128), 256, 0, stream>>>(WT, atomG1, G2TF1, G2nf);
  kG1<<<dim3(4, 128), 256, 0, stream>>>(G2TF1, xbfF0, atomG1);   // G1 overwrites atom_bf (dead)

  kFeatAll<<<dim3(4, 128, 4), 256, 0, stream>>>(KhT, atomG1, G2nf, diag, fc_b, eps,
                                                biases, att_s, att_n,
                                                xbfF0, G2TF1, fT2, fT3, a_s, a_n);
  kAttnAll<<<dim3(8, 128, 4), 256, 0, stream>>>(xbits, a_s, a_n, att_b,
                                                xbfF0, G2TF1, fT2, fT3, out, out2);
}

// Round 6
// 296.435 us; speedup vs baseline: 13.5049x; 1.0634x over previous
//
#include <hip/hip_runtime.h>

typedef __attribute__((ext_vector_type(8))) short bf16x8;
typedef __attribute__((ext_vector_type(4))) short short4v;
typedef __attribute__((ext_vector_type(4))) float f32x4;

// B=128, N=256, D=256, H=4 ; per-batch matrices are [256][256] (65536 elems)

__device__ __forceinline__ float b2f(short s){
  unsigned u = ((unsigned)(unsigned short)s) << 16;
  return __builtin_bit_cast(float, u);
}
__device__ __forceinline__ short f2b(float f){
  unsigned u = __builtin_bit_cast(unsigned, f);
  u = (u + 0x7FFFu + ((u >> 16) & 1u)) >> 16;
  return (short)(unsigned short)u;
}

// -------- transpose-convert f32 [256][256] -> bf16 ^T : z=0 fc_w->WT, z=1..4 kernels->KhT --------
__global__ __launch_bounds__(256) void ktrans(const float* __restrict__ fcw, const float* __restrict__ kers,
                                              short* __restrict__ WT, short* __restrict__ KhT){
  __shared__ float tile[32][33];
  int z = blockIdx.z;
  const float* src = (z == 0) ? fcw : (kers + (z-1)*65536);
  short* dst = (z == 0) ? WT : (KhT + (z-1)*65536);
  int x0 = blockIdx.x*32, y0 = blockIdx.y*32;
  int tx = threadIdx.x & 31, ty = threadIdx.x >> 5;
  #pragma unroll
  for (int i = 0; i < 32; i += 8) tile[ty+i][tx] = src[(y0+ty+i)*256 + x0+tx];
  __syncthreads();
  #pragma unroll
  for (int i = 0; i < 32; i += 8) dst[(x0+ty+i)*256 + y0+tx] = f2b(tile[tx][ty+i]);
}

// -------- prep: z=0 atom f32->bf16 ; z=1 x f32->bf16 + bitfields + diag. grid (8,128,2) --------
__global__ __launch_bounds__(256) void kprep(const float* __restrict__ atom, const float* __restrict__ x,
                                             short* __restrict__ atom_bf, short* __restrict__ xbf,
                                             unsigned* __restrict__ xbits, float* __restrict__ diag){
  int b = blockIdx.y;
  int row = blockIdx.x*32 + (threadIdx.x >> 3);
  int seg = threadIdx.x & 7;
  if (blockIdx.z == 0){
    const float* p = atom + b*65536 + row*256 + seg*32;
    short* q = atom_bf + b*65536 + row*256 + seg*32;
    #pragma unroll
    for (int k = 0; k < 4; k++){
      f32x4 a = ((const f32x4*)p)[k*2], c = ((const f32x4*)p)[k*2+1];
      bf16x8 o;
      #pragma unroll
      for (int e = 0; e < 4; e++){ o[e] = f2b(a[e]); o[4+e] = f2b(c[e]); }
      ((bf16x8*)q)[k] = o;
    }
  } else {
    const float* p = x + b*65536 + row*256 + seg*32;
    float v[32];
    #pragma unroll
    for (int k = 0; k < 8; k++){
      f32x4 qv = ((const f32x4*)p)[k];
      #pragma unroll
      for (int e = 0; e < 4; e++) v[k*4+e] = qv[e];
    }
    unsigned bits = 0u;
    #pragma unroll
    for (int e = 0; e < 32; e++) if (v[e] > 0.5f) bits |= (1u << e);
    xbits[(b*256 + row)*8 + seg] = bits;
    short* q = xbf + b*65536 + row*256 + seg*32;
    #pragma unroll
    for (int k = 0; k < 4; k++){
      bf16x8 o;
      #pragma unroll
      for (int e = 0; e < 8; e++) o[e] = f2b(v[k*8+e]);
      ((bf16x8*)q)[k] = o;
    }
    if ((row >> 5) == seg) diag[b*256 + row] = v[row & 31];
  }
}

// -------- G2 = atom @ W : G2T[f][m] (scalar) + G2nf[m][f] (vector C^T). grid (4,128) --------
__global__ __launch_bounds__(256) void kG2(const short* __restrict__ WT, const short* __restrict__ atomb,
                                           short* __restrict__ G2T, short* __restrict__ G2nf){
  int b = blockIdx.y;
  int tr = (blockIdx.x >> 1) * 128, tc = (blockIdx.x & 1) * 128;
  int lane = threadIdx.x & 63, wave = threadIdx.x >> 6;
  int wr = (wave >> 1) * 64, wc = (wave & 1) * 64;
  const short* Y = atomb + b * 65536;
  int r0 = tr + wr + (lane & 15);
  int c0 = tc + wc + (lane & 15);
  int koff = (lane >> 4) * 8;
  f32x4 acc[4][4] = {};
  for (int k0 = 0; k0 < 256; k0 += 32){
    bf16x8 af[4], bfr[4];
    #pragma unroll
    for (int i = 0; i < 4; i++) af[i]  = *(const bf16x8*)(WT + (r0 + i*16)*256 + k0 + koff);
    #pragma unroll
    for (int j = 0; j < 4; j++) bfr[j] = *(const bf16x8*)(Y  + (c0 + j*16)*256 + k0 + koff);
    #pragma unroll
    for (int i = 0; i < 4; i++)
      #pragma unroll
      for (int j = 0; j < 4; j++)
        acc[i][j] = __builtin_amdgcn_mfma_f32_16x16x32_bf16(af[i], bfr[j], acc[i][j], 0, 0, 0);
  }
  int fi0 = tr + wr + (lane >> 4) * 4;
  int mj0 = tc + wc + (lane & 15);
  #pragma unroll
  for (int i = 0; i < 4; i++)
    #pragma unroll
    for (int j = 0; j < 4; j++){
      short4v v;
      #pragma unroll
      for (int r = 0; r < 4; r++) v[r] = f2b(acc[i][j][r]);
      *(short4v*)(G2nf + b*65536 + (mj0 + j*16)*256 + fi0 + i*16) = v;   // [m][f]
      #pragma unroll
      for (int r = 0; r < 4; r++)
        G2T[b*65536 + (fi0 + i*16 + r)*256 + mj0 + j*16] = v[r];         // [f][m]
    }
}

// -------- G1 = x @ G2 : P(G2T, xbf), C^T store G1[n][f]. grid (4,128) --------
__global__ __launch_bounds__(256) void kG1(const short* __restrict__ G2T, const short* __restrict__ xbf,
                                           short* __restrict__ G1){
  int b = blockIdx.y;
  int tr = (blockIdx.x >> 1) * 128, tc = (blockIdx.x & 1) * 128;
  int lane = threadIdx.x & 63, wave = threadIdx.x >> 6;
  int wr = (wave >> 1) * 64, wc = (wave & 1) * 64;
  const short* X = G2T + b * 65536;
  const short* Y = xbf + b * 65536;
  int r0 = tr + wr + (lane & 15);
  int c0 = tc + wc + (lane & 15);
  int koff = (lane >> 4) * 8;
  f32x4 acc[4][4] = {};
  for (int k0 = 0; k0 < 256; k0 += 32){
    bf16x8 af[4], bfr[4];
    #pragma unroll
    for (int i = 0; i < 4; i++) af[i]  = *(const bf16x8*)(X + (r0 + i*16)*256 + k0 + koff);
    #pragma unroll
    for (int j = 0; j < 4; j++) bfr[j] = *(const bf16x8*)(Y + (c0 + j*16)*256 + k0 + koff);
    #pragma unroll
    for (int i = 0; i < 4; i++)
      #pragma unroll
      for (int j = 0; j < 4; j++)
        acc[i][j] = __builtin_amdgcn_mfma_f32_16x16x32_bf16(af[i], bfr[j], acc[i][j], 0, 0, 0);
  }
  int fi0 = tr + wr + (lane >> 4) * 4;
  int nj0 = tc + wc + (lane & 15);
  #pragma unroll
  for (int i = 0; i < 4; i++)
    #pragma unroll
    for (int j = 0; j < 4; j++){
      short4v v;
      #pragma unroll
      for (int r = 0; r < 4; r++) v[r] = f2b(acc[i][j][r]);
      *(short4v*)(G1 + b*65536 + (nj0 + j*16)*256 + fi0 + i*16) = v;     // [n][f]
    }
}

// -------- featT_h[o][n] = (h1_h @ K_h + bias)^T for ALL h; h1 rebuilt on the fly --------
// 1-D grid 512, XCD-swizzled: b on xcd b%8. Block: 2x2 wave grid, wave = 128 o x 32 n. Loops h=0..3.
__global__ __launch_bounds__(256) void kFeatAll(const short* __restrict__ KhT, const short* __restrict__ G1,
                                                const short* __restrict__ G2nf, const float* __restrict__ diag,
                                                const float* __restrict__ fcb, const float* __restrict__ epsv,
                                                const float* __restrict__ biases, const float* __restrict__ atts,
                                                const float* __restrict__ attn,
                                                short* __restrict__ fT0, short* __restrict__ fT1,
                                                short* __restrict__ fT2, short* __restrict__ fT3,
                                                float* __restrict__ a_s, float* __restrict__ a_n){
  __shared__ float red_s[4][32];
  __shared__ float red_n[4][32];
  int wg = blockIdx.x;                        // 0..511
  int b  = (wg & 7) + ((wg >> 5) << 3);       // xcd-group: all 4 n-tiles of b on xcd b%8
  int tc = ((wg >> 3) & 3) * 64;
  int tid = threadIdx.x, lane = tid & 63, w = tid >> 6;
  const short* G1b = G1 + b*65536;
  const short* G2b = G2nf + b*65536;
  int wro = (w >> 1) * 128, wcn = (w & 1) * 32;
  int lr = lane & 15, lq = lane >> 4;
  int koff = lq * 8;
  int nj[2]; float dg[2];
  #pragma unroll
  for (int j = 0; j < 2; j++){
    nj[j] = tc + wcn + j*16 + lr;
    dg[j] = diag[b*256 + nj[j]];
  }

  for (int h = 0; h < 4; ++h){
    short* featT = (h==0)?fT0:(h==1)?fT1:(h==2)?fT2:fT3;
    const short* KA = KhT + h*65536;
    float epsm1 = epsv[h] - 1.0f;
    float cj[2] = { epsm1 * dg[0], epsm1 * dg[1] };
    f32x4 acc[8][2] = {};
    for (int k0 = 0; k0 < 256; k0 += 32){
      f32x4 f0 = *(const f32x4*)(fcb + k0 + koff);
      f32x4 f1 = *(const f32x4*)(fcb + k0 + koff + 4);
      bf16x8 hb[2];
      #pragma unroll
      for (int j = 0; j < 2; j++){
        bf16x8 g1 = *(const bf16x8*)(G1b + nj[j]*256 + k0 + koff);
        bf16x8 g2 = *(const bf16x8*)(G2b + nj[j]*256 + k0 + koff);
        bf16x8 o;
        #pragma unroll
        for (int e = 0; e < 8; e++){
          float fb = (e < 4) ? f0[e] : f1[e-4];
          float v = b2f(g1[e]) + cj[j]*b2f(g2[e]) + fb;
          v = v > 0.f ? v : 0.01f*v;
          o[e] = f2b(v);
        }
        hb[j] = o;
      }
      #pragma unroll
      for (int i = 0; i < 8; i++){
        bf16x8 af = *(const bf16x8*)(KA + (wro + i*16 + lr)*256 + k0 + koff);
        acc[i][0] = __builtin_amdgcn_mfma_f32_16x16x32_bf16(af, hb[0], acc[i][0], 0, 0, 0);
        acc[i][1] = __builtin_amdgcn_mfma_f32_16x16x32_bf16(af, hb[1], acc[i][1], 0, 0, 0);
      }
    }
    int c4 = lq * 4;
    float ps[2] = {0.f, 0.f}, pn[2] = {0.f, 0.f};
    #pragma unroll
    for (int i = 0; i < 8; i++){
      int ob = wro + i*16 + c4;
      f32x4 bi  = *(const f32x4*)(biases + h*256 + ob);
      f32x4 ws4 = *(const f32x4*)(atts   + h*256 + ob);
      f32x4 wn4 = *(const f32x4*)(attn   + h*256 + ob);
      #pragma unroll
      for (int r = 0; r < 4; r++){
        #pragma unroll
        for (int j = 0; j < 2; j++){
          float fv = acc[i][j][r] + bi[r];
          featT[b*65536 + (ob + r)*256 + nj[j]] = f2b(fv);
          ps[j] += fv * ws4[r];
          pn[j] += fv * wn4[r];
        }
      }
    }
    #pragma unroll
    for (int j = 0; j < 2; j++){
      float s = ps[j]; s += __shfl_xor(s, 16); s += __shfl_xor(s, 32);
      float nv = pn[j]; nv += __shfl_xor(nv, 16); nv += __shfl_xor(nv, 32);
      if (lane < 16){
        red_s[w][j*16 + lane] = s;
        red_n[w][j*16 + lane] = nv;
      }
    }
    __syncthreads();
    if (tid < 64){
      int g = tid >> 5;       // 0: waves {0,2} (wcn=0) ; 1: waves {1,3} (wcn=32)
      int idx = tid & 31;
      float ss = red_s[g][idx] + red_s[g+2][idx];
      float nn = red_n[g][idx] + red_n[g+2][idx];
      a_s[(h*128 + b)*256 + tc + tid] = ss;
      a_n[(h*128 + b)*256 + tc + tid] = nn;
    }
    __syncthreads();
  }
}

// -------- softmax(elu(a_s+a_n)+mask) ; node = P @ feat ; f32 out ; att dump h==3 --------
// 1-D grid 4096, XCD-swizzled: the 8 i-tiles of group (h,b) share xcd b%8.
__global__ __launch_bounds__(256) void kAttnAll(const unsigned* __restrict__ xbits,
                                                const float* __restrict__ a_s, const float* __restrict__ a_n,
                                                const float* __restrict__ attbv,
                                                const short* __restrict__ fT0, const short* __restrict__ fT1,
                                                const short* __restrict__ fT2, const short* __restrict__ fT3,
                                                float* __restrict__ out, float* __restrict__ out2){
  __shared__ __align__(16) short Pbuf[32][264];
  int wg = blockIdx.x;                        // 0..4095
  int g  = (wg & 7) + ((wg >> 6) << 3);       // flat (h,b) group 0..511 ; xcd = g%8 = b%8
  int it0 = ((wg >> 3) & 7) * 32;
  int h = g >> 7, b = g & 127;
  int tid = threadIdx.x, lane = tid & 63, w = tid >> 6;
  const short* featT = (h==0)?fT0:(h==1)?fT1:(h==2)?fT2:fT3;
  const float* asp = a_s + (h*128 + b)*256;
  const float* anp = a_n + (h*128 + b)*256;

  // phase A: 32 rows x (8 segs x 32 cols)
  int row = tid >> 3, seg = tid & 7;
  int i = it0 + row;
  float asv = asp[i] + attbv[h];
  unsigned bits = xbits[(b*256 + i)*8 + seg];
  const f32x4* an4 = (const f32x4*)(anp + seg*32);
  float Lv[32];
  float mx = -3.0e38f;
  #pragma unroll
  for (int kk = 0; kk < 8; kk++){
    f32x4 a = an4[kk];
    #pragma unroll
    for (int e = 0; e < 4; e++){
      float s = asv + a[e];
      float el = s > 0.f ? s : (__expf(s) - 1.0f);
      float L = el + (((bits >> (kk*4+e)) & 1u) ? 0.f : -1.0e10f);
      Lv[kk*4+e] = L;
      mx = fmaxf(mx, L);
    }
  }
  mx = fmaxf(mx, __shfl_xor(mx, 1));
  mx = fmaxf(mx, __shfl_xor(mx, 2));
  mx = fmaxf(mx, __shfl_xor(mx, 4));
  float sum = 0.f;
  #pragma unroll
  for (int e = 0; e < 32; e++){ float p = __expf(Lv[e] - mx); Lv[e] = p; sum += p; }
  sum += __shfl_xor(sum, 1);
  sum += __shfl_xor(sum, 2);
  sum += __shfl_xor(sum, 4);
  float inv = 1.0f / sum;
  #pragma unroll
  for (int kk = 0; kk < 4; kk++){
    bf16x8 pv;
    #pragma unroll
    for (int e = 0; e < 8; e++) pv[e] = f2b(Lv[kk*8+e] * inv);
    *(bf16x8*)&Pbuf[row][seg*32 + kk*8] = pv;
  }
  if (h == 3){
    float* o2 = out2 + b*65536 + i*256 + seg*32;
    #pragma unroll
    for (int kk = 0; kk < 8; kk++){
      f32x4 v;
      #pragma unroll
      for (int e = 0; e < 4; e++) v[e] = Lv[kk*4+e] * inv;
      *(f32x4*)(o2 + kk*4) = v;
    }
  }
  __syncthreads();

  // phase B: nodeT = P(featT, Pbuf) ; C^T-write f32 to out
  int o0w = w * 64;
  const short* F = featT + b * 65536;
  int orow = o0w + (lane & 15);
  int koff = (lane >> 4) * 8;
  f32x4 acc[4][2] = {};
  for (int k0 = 0; k0 < 256; k0 += 32){
    bf16x8 af[4], bfr[2];
    #pragma unroll
    for (int ii = 0; ii < 4; ii++) af[ii] = *(const bf16x8*)(F + (orow + ii*16)*256 + k0 + koff);
    #pragma unroll
    for (int jf = 0; jf < 2; jf++) bfr[jf] = *(const bf16x8*)&Pbuf[jf*16 + (lane & 15)][k0 + koff];
    #pragma unroll
    for (int ii = 0; ii < 4; ii++)
      #pragma unroll
      for (int jf = 0; jf < 2; jf++)
        acc[ii][jf] = __builtin_amdgcn_mfma_f32_16x16x32_bf16(af[ii], bfr[jf], acc[ii][jf], 0, 0, 0);
  }
  int oo0 = o0w + (lane >> 4) * 4;
  #pragma unroll
  for (int ii = 0; ii < 4; ii++)
    #pragma unroll
    for (int jf = 0; jf < 2; jf++){
      int iW = it0 + jf*16 + (lane & 15);
      *(f32x4*)(out + (size_t)(b*256 + iW)*1024 + h*256 + oo0 + ii*16) = acc[ii][jf];
    }
}

extern "C" void kernel_launch(void* const* d_in, const int* in_sizes, int n_in,
                              void* d_out, int out_size, void* d_ws, size_t ws_size,
                              hipStream_t stream) {
  const float* atom   = (const float*)d_in[0];
  const float* x      = (const float*)d_in[1];
  const float* fc_w   = (const float*)d_in[2];
  const float* fc_b   = (const float*)d_in[3];
  const float* kers   = (const float*)d_in[4];
  const float* att_s  = (const float*)d_in[5];
  const float* att_n  = (const float*)d_in[6];
  const float* eps    = (const float*)d_in[7];
  const float* biases = (const float*)d_in[8];
  const float* att_b  = (const float*)d_in[9];

  // ws layout, 98.8 MiB total (ws_size >= 104 MiB established in R3).
  char* w = (char*)d_ws;
  short* WT      = (short*)(w);                      // 128 KB
  short* KhT     = (short*)(w + 131072);             // 512 KB
  float* diag    = (float*)(w + 655360);             // 128 KB
  float* a_s     = (float*)(w + 786432);             // 512 KB  [h][b][n]
  float* a_n     = (float*)(w + 1310720);            // 512 KB
  unsigned* xbits= (unsigned*)(w + 1835008);         // 1 MB
  short* atomG1  = (short*)(w + 2883584);            // 16 MB: atom_bf, then G1
  short* xbfF0   = (short*)(w + 19660800);           // 16 MB: x_bf, then featT[0]
  short* G2TF1   = (short*)(w + 36438016);           // 16 MB: G2T, then featT[1]
  short* G2nf    = (short*)(w + 53215232);           // 16 MB
  short* fT2     = (short*)(w + 69992448);           // 16 MB
  short* fT3     = (short*)(w + 86769664);           // 16 MB

  float* out  = (float*)d_out;
  float* out2 = out + 33554432;  // B*N*H*D floats

  ktrans<<<dim3(8, 8, 5), 256, 0, stream>>>(fc_w, kers, WT, KhT);
  kprep<<<dim3(8, 128, 2), 256, 0, stream>>>(atom, x, atomG1, xbfF0, xbits, diag);
  kG2<<<dim3(4, 128), 256, 0, stream>>>(WT, atomG1, G2TF1, G2nf);
  kG1<<<dim3(4, 128), 256, 0, stream>>>(G2TF1, xbfF0, atomG1);   // G1 overwrites atom_bf (dead)

  kFeatAll<<<dim3(512), 256, 0, stream>>>(KhT, atomG1, G2nf, diag, fc_b, eps,
                                          biases, att_s, att_n,
                                          xbfF0, G2TF1, fT2, fT3, a_s, a_n);
  kAttnAll<<<dim3(4096), 256, 0, stream>>>(xbits, a_s, a_n, att_b,
                                           xbfF0, G2TF1, fT2, fT3, out, out2);
}

// Round 7
// 282.091 us; speedup vs baseline: 14.1916x; 1.0508x over previous
//
#include <hip/hip_runtime.h>

typedef __attribute__((ext_vector_type(8))) short bf16x8;
typedef __attribute__((ext_vector_type(4))) short short4v;
typedef __attribute__((ext_vector_type(4))) float f32x4;

// B=128, N=256, D=256, H=4 ; per-batch matrices are [256][256] (65536 elems)

__device__ __forceinline__ float b2f(short s){
  unsigned u = ((unsigned)(unsigned short)s) << 16;
  return __builtin_bit_cast(float, u);
}
__device__ __forceinline__ short f2b(float f){
  unsigned u = __builtin_bit_cast(unsigned, f);
  u = (u + 0x7FFFu + ((u >> 16) & 1u)) >> 16;
  return (short)(unsigned short)u;
}

// -------- transpose-convert f32 [256][256] -> bf16 ^T : z=0 fc_w->WT, z=1..4 kernels->KhT --------
__global__ __launch_bounds__(256) void ktrans(const float* __restrict__ fcw, const float* __restrict__ kers,
                                              short* __restrict__ WT, short* __restrict__ KhT){
  __shared__ float tile[32][33];
  int z = blockIdx.z;
  const float* src = (z == 0) ? fcw : (kers + (z-1)*65536);
  short* dst = (z == 0) ? WT : (KhT + (z-1)*65536);
  int x0 = blockIdx.x*32, y0 = blockIdx.y*32;
  int tx = threadIdx.x & 31, ty = threadIdx.x >> 5;
  #pragma unroll
  for (int i = 0; i < 32; i += 8) tile[ty+i][tx] = src[(y0+ty+i)*256 + x0+tx];
  __syncthreads();
  #pragma unroll
  for (int i = 0; i < 32; i += 8) dst[(x0+ty+i)*256 + y0+tx] = f2b(tile[tx][ty+i]);
}

// -------- prep: z=0 atom f32->bf16 ; z=1 x f32->bf16 + bitfields + diag. grid (8,128,2) --------
__global__ __launch_bounds__(256) void kprep(const float* __restrict__ atom, const float* __restrict__ x,
                                             short* __restrict__ atom_bf, short* __restrict__ xbf,
                                             unsigned* __restrict__ xbits, float* __restrict__ diag){
  int b = blockIdx.y;
  int row = blockIdx.x*32 + (threadIdx.x >> 3);
  int seg = threadIdx.x & 7;
  if (blockIdx.z == 0){
    const float* p = atom + b*65536 + row*256 + seg*32;
    short* q = atom_bf + b*65536 + row*256 + seg*32;
    #pragma unroll
    for (int k = 0; k < 4; k++){
      f32x4 a = ((const f32x4*)p)[k*2], c = ((const f32x4*)p)[k*2+1];
      bf16x8 o;
      #pragma unroll
      for (int e = 0; e < 4; e++){ o[e] = f2b(a[e]); o[4+e] = f2b(c[e]); }
      ((bf16x8*)q)[k] = o;
    }
  } else {
    const float* p = x + b*65536 + row*256 + seg*32;
    float v[32];
    #pragma unroll
    for (int k = 0; k < 8; k++){
      f32x4 qv = ((const f32x4*)p)[k];
      #pragma unroll
      for (int e = 0; e < 4; e++) v[k*4+e] = qv[e];
    }
    unsigned bits = 0u;
    #pragma unroll
    for (int e = 0; e < 32; e++) if (v[e] > 0.5f) bits |= (1u << e);
    xbits[(b*256 + row)*8 + seg] = bits;
    short* q = xbf + b*65536 + row*256 + seg*32;
    #pragma unroll
    for (int k = 0; k < 4; k++){
      bf16x8 o;
      #pragma unroll
      for (int e = 0; e < 8; e++) o[e] = f2b(v[k*8+e]);
      ((bf16x8*)q)[k] = o;
    }
    if ((row >> 5) == seg) diag[b*256 + row] = v[row & 31];
  }
}

// -------- G2 = atom @ W : G2T[f][m] (scalar) + G2nf[m][f] (vector C^T). grid (4,128) --------
__global__ __launch_bounds__(256) void kG2(const short* __restrict__ WT, const short* __restrict__ atomb,
                                           short* __restrict__ G2T, short* __restrict__ G2nf){
  int b = blockIdx.y;
  int tr = (blockIdx.x >> 1) * 128, tc = (blockIdx.x & 1) * 128;
  int lane = threadIdx.x & 63, wave = threadIdx.x >> 6;
  int wr = (wave >> 1) * 64, wc = (wave & 1) * 64;
  const short* Y = atomb + b * 65536;
  int r0 = tr + wr + (lane & 15);
  int c0 = tc + wc + (lane & 15);
  int koff = (lane >> 4) * 8;
  f32x4 acc[4][4] = {};
  for (int k0 = 0; k0 < 256; k0 += 32){
    bf16x8 af[4], bfr[4];
    #pragma unroll
    for (int i = 0; i < 4; i++) af[i]  = *(const bf16x8*)(WT + (r0 + i*16)*256 + k0 + koff);
    #pragma unroll
    for (int j = 0; j < 4; j++) bfr[j] = *(const bf16x8*)(Y  + (c0 + j*16)*256 + k0 + koff);
    #pragma unroll
    for (int i = 0; i < 4; i++)
      #pragma unroll
      for (int j = 0; j < 4; j++)
        acc[i][j] = __builtin_amdgcn_mfma_f32_16x16x32_bf16(af[i], bfr[j], acc[i][j], 0, 0, 0);
  }
  int fi0 = tr + wr + (lane >> 4) * 4;
  int mj0 = tc + wc + (lane & 15);
  #pragma unroll
  for (int i = 0; i < 4; i++)
    #pragma unroll
    for (int j = 0; j < 4; j++){
      short4v v;
      #pragma unroll
      for (int r = 0; r < 4; r++) v[r] = f2b(acc[i][j][r]);
      *(short4v*)(G2nf + b*65536 + (mj0 + j*16)*256 + fi0 + i*16) = v;   // [m][f]
      #pragma unroll
      for (int r = 0; r < 4; r++)
        G2T[b*65536 + (fi0 + i*16 + r)*256 + mj0 + j*16] = v[r];         // [f][m]
    }
}

// -------- G1 = x @ G2 : P(G2T, xbf), C^T store G1[n][f]. grid (4,128) --------
__global__ __launch_bounds__(256) void kG1(const short* __restrict__ G2T, const short* __restrict__ xbf,
                                           short* __restrict__ G1){
  int b = blockIdx.y;
  int tr = (blockIdx.x >> 1) * 128, tc = (blockIdx.x & 1) * 128;
  int lane = threadIdx.x & 63, wave = threadIdx.x >> 6;
  int wr = (wave >> 1) * 64, wc = (wave & 1) * 64;
  const short* X = G2T + b * 65536;
  const short* Y = xbf + b * 65536;
  int r0 = tr + wr + (lane & 15);
  int c0 = tc + wc + (lane & 15);
  int koff = (lane >> 4) * 8;
  f32x4 acc[4][4] = {};
  for (int k0 = 0; k0 < 256; k0 += 32){
    bf16x8 af[4], bfr[4];
    #pragma unroll
    for (int i = 0; i < 4; i++) af[i]  = *(const bf16x8*)(X + (r0 + i*16)*256 + k0 + koff);
    #pragma unroll
    for (int j = 0; j < 4; j++) bfr[j] = *(const bf16x8*)(Y + (c0 + j*16)*256 + k0 + koff);
    #pragma unroll
    for (int i = 0; i < 4; i++)
      #pragma unroll
      for (int j = 0; j < 4; j++)
        acc[i][j] = __builtin_amdgcn_mfma_f32_16x16x32_bf16(af[i], bfr[j], acc[i][j], 0, 0, 0);
  }
  int fi0 = tr + wr + (lane >> 4) * 4;
  int nj0 = tc + wc + (lane & 15);
  #pragma unroll
  for (int i = 0; i < 4; i++)
    #pragma unroll
    for (int j = 0; j < 4; j++){
      short4v v;
      #pragma unroll
      for (int r = 0; r < 4; r++) v[r] = f2b(acc[i][j][r]);
      *(short4v*)(G1 + b*65536 + (nj0 + j*16)*256 + fi0 + i*16) = v;     // [n][f]
    }
}

// -------- featT_h[o][n] = (h1_h @ K_h + bias)^T ; h1 rebuilt on the fly; a_s/a_n reduce --------
// 1-D grid 2048, XCD-swizzled: the 16 blocks (4 h x 4 n-tiles) of batch b sit on xcd b%8.
// Block: 2x2 wave grid, wave = 128 o x 32 n.
__global__ __launch_bounds__(256) void kFeatAll(const short* __restrict__ KhT, const short* __restrict__ G1,
                                                const short* __restrict__ G2nf, const float* __restrict__ diag,
                                                const float* __restrict__ fcb, const float* __restrict__ epsv,
                                                const float* __restrict__ biases, const float* __restrict__ atts,
                                                const float* __restrict__ attn,
                                                short* __restrict__ fT0, short* __restrict__ fT1,
                                                short* __restrict__ fT2, short* __restrict__ fT3,
                                                float* __restrict__ a_s, float* __restrict__ a_n){
  __shared__ float red_s[4][32];
  __shared__ float red_n[4][32];
  int wg = blockIdx.x;                 // 0..2047
  int xcd = wg & 7;
  int idx = wg >> 3;                   // 0..255 within xcd
  int b   = xcd + ((idx >> 4) << 3);   // 16 batches per xcd
  int sub = idx & 15;
  int h   = sub >> 2;
  int tc  = (sub & 3) * 64;
  int tid = threadIdx.x, lane = tid & 63, w = tid >> 6;
  short* featT = (h==0)?fT0:(h==1)?fT1:(h==2)?fT2:fT3;
  float epsm1 = epsv[h] - 1.0f;
  const short* KA = KhT + h*65536;
  const short* G1b = G1 + b*65536;
  const short* G2b = G2nf + b*65536;
  int wro = (w >> 1) * 128, wcn = (w & 1) * 32;
  int lr = lane & 15, lq = lane >> 4;
  int koff = lq * 8;
  int nj[2]; float cj[2];
  #pragma unroll
  for (int j = 0; j < 2; j++){
    nj[j] = tc + wcn + j*16 + lr;
    cj[j] = epsm1 * diag[b*256 + nj[j]];
  }
  f32x4 acc[8][2] = {};
  for (int k0 = 0; k0 < 256; k0 += 32){
    f32x4 f0 = *(const f32x4*)(fcb + k0 + koff);
    f32x4 f1 = *(const f32x4*)(fcb + k0 + koff + 4);
    bf16x8 hb[2];
    #pragma unroll
    for (int j = 0; j < 2; j++){
      bf16x8 g1 = *(const bf16x8*)(G1b + nj[j]*256 + k0 + koff);
      bf16x8 g2 = *(const bf16x8*)(G2b + nj[j]*256 + k0 + koff);
      bf16x8 o;
      #pragma unroll
      for (int e = 0; e < 8; e++){
        float fb = (e < 4) ? f0[e] : f1[e-4];
        float v = b2f(g1[e]) + cj[j]*b2f(g2[e]) + fb;
        v = v > 0.f ? v : 0.01f*v;
        o[e] = f2b(v);
      }
      hb[j] = o;
    }
    #pragma unroll
    for (int i = 0; i < 8; i++){
      bf16x8 af = *(const bf16x8*)(KA + (wro + i*16 + lr)*256 + k0 + koff);
      acc[i][0] = __builtin_amdgcn_mfma_f32_16x16x32_bf16(af, hb[0], acc[i][0], 0, 0, 0);
      acc[i][1] = __builtin_amdgcn_mfma_f32_16x16x32_bf16(af, hb[1], acc[i][1], 0, 0, 0);
    }
  }
  int c4 = lq * 4;
  float ps[2] = {0.f, 0.f}, pn[2] = {0.f, 0.f};
  #pragma unroll
  for (int i = 0; i < 8; i++){
    int ob = wro + i*16 + c4;
    f32x4 bi  = *(const f32x4*)(biases + h*256 + ob);
    f32x4 ws4 = *(const f32x4*)(atts   + h*256 + ob);
    f32x4 wn4 = *(const f32x4*)(attn   + h*256 + ob);
    #pragma unroll
    for (int r = 0; r < 4; r++){
      #pragma unroll
      for (int j = 0; j < 2; j++){
        float fv = acc[i][j][r] + bi[r];
        featT[b*65536 + (ob + r)*256 + nj[j]] = f2b(fv);
        ps[j] += fv * ws4[r];
        pn[j] += fv * wn4[r];
      }
    }
  }
  #pragma unroll
  for (int j = 0; j < 2; j++){
    float s = ps[j]; s += __shfl_xor(s, 16); s += __shfl_xor(s, 32);
    float nv = pn[j]; nv += __shfl_xor(nv, 16); nv += __shfl_xor(nv, 32);
    if (lane < 16){
      red_s[w][j*16 + lane] = s;
      red_n[w][j*16 + lane] = nv;
    }
  }
  __syncthreads();
  if (tid < 64){
    int g = tid >> 5;       // 0: waves {0,2} (wcn=0) ; 1: waves {1,3} (wcn=32)
    int idx2 = tid & 31;
    float ss = red_s[g][idx2] + red_s[g+2][idx2];
    float nn = red_n[g][idx2] + red_n[g+2][idx2];
    a_s[(h*128 + b)*256 + tc + tid] = ss;
    a_n[(h*128 + b)*256 + tc + tid] = nn;
  }
}

// -------- softmax(elu(a_s+a_n)+mask) ; node = P @ feat ; f32 out ; att dump h==3 --------
// 1-D grid 4096, XCD-swizzled: the 8 i-tiles of group (h,b) share xcd b%8.
__global__ __launch_bounds__(256) void kAttnAll(const unsigned* __restrict__ xbits,
                                                const float* __restrict__ a_s, const float* __restrict__ a_n,
                                                const float* __restrict__ attbv,
                                                const short* __restrict__ fT0, const short* __restrict__ fT1,
                                                const short* __restrict__ fT2, const short* __restrict__ fT3,
                                                float* __restrict__ out, float* __restrict__ out2){
  __shared__ __align__(16) short Pbuf[32][264];
  int wg = blockIdx.x;                        // 0..4095
  int g  = (wg & 7) + ((wg >> 6) << 3);       // flat (h,b) group 0..511 ; xcd = g%8 = b%8
  int it0 = ((wg >> 3) & 7) * 32;
  int h = g >> 7, b = g & 127;
  int tid = threadIdx.x, lane = tid & 63, w = tid >> 6;
  const short* featT = (h==0)?fT0:(h==1)?fT1:(h==2)?fT2:fT3;
  const float* asp = a_s + (h*128 + b)*256;
  const float* anp = a_n + (h*128 + b)*256;

  // phase A: 32 rows x (8 segs x 32 cols)
  int row = tid >> 3, seg = tid & 7;
  int i = it0 + row;
  float asv = asp[i] + attbv[h];
  unsigned bits = xbits[(b*256 + i)*8 + seg];
  const f32x4* an4 = (const f32x4*)(anp + seg*32);
  float Lv[32];
  float mx = -3.0e38f;
  #pragma unroll
  for (int kk = 0; kk < 8; kk++){
    f32x4 a = an4[kk];
    #pragma unroll
    for (int e = 0; e < 4; e++){
      float s = asv + a[e];
      float el = s > 0.f ? s : (__expf(s) - 1.0f);
      float L = el + (((bits >> (kk*4+e)) & 1u) ? 0.f : -1.0e10f);
      Lv[kk*4+e] = L;
      mx = fmaxf(mx, L);
    }
  }
  mx = fmaxf(mx, __shfl_xor(mx, 1));
  mx = fmaxf(mx, __shfl_xor(mx, 2));
  mx = fmaxf(mx, __shfl_xor(mx, 4));
  float sum = 0.f;
  #pragma unroll
  for (int e = 0; e < 32; e++){ float p = __expf(Lv[e] - mx); Lv[e] = p; sum += p; }
  sum += __shfl_xor(sum, 1);
  sum += __shfl_xor(sum, 2);
  sum += __shfl_xor(sum, 4);
  float inv = 1.0f / sum;
  #pragma unroll
  for (int kk = 0; kk < 4; kk++){
    bf16x8 pv;
    #pragma unroll
    for (int e = 0; e < 8; e++) pv[e] = f2b(Lv[kk*8+e] * inv);
    *(bf16x8*)&Pbuf[row][seg*32 + kk*8] = pv;
  }
  if (h == 3){
    float* o2 = out2 + b*65536 + i*256 + seg*32;
    #pragma unroll
    for (int kk = 0; kk < 8; kk++){
      f32x4 v;
      #pragma unroll
      for (int e = 0; e < 4; e++) v[e] = Lv[kk*4+e] * inv;
      *(f32x4*)(o2 + kk*4) = v;
    }
  }
  __syncthreads();

  // phase B: nodeT = P(featT, Pbuf) ; C^T-write f32 to out
  int o0w = w * 64;
  const short* F = featT + b * 65536;
  int orow = o0w + (lane & 15);
  int koff = (lane >> 4) * 8;
  f32x4 acc[4][2] = {};
  for (int k0 = 0; k0 < 256; k0 += 32){
    bf16x8 af[4], bfr[2];
    #pragma unroll
    for (int ii = 0; ii < 4; ii++) af[ii] = *(const bf16x8*)(F + (orow + ii*16)*256 + k0 + koff);
    #pragma unroll
    for (int jf = 0; jf < 2; jf++) bfr[jf] = *(const bf16x8*)&Pbuf[jf*16 + (lane & 15)][k0 + koff];
    #pragma unroll
    for (int ii = 0; ii < 4; ii++)
      #pragma unroll
      for (int jf = 0; jf < 2; jf++)
        acc[ii][jf] = __builtin_amdgcn_mfma_f32_16x16x32_bf16(af[ii], bfr[jf], acc[ii][jf], 0, 0, 0);
  }
  int oo0 = o0w + (lane >> 4) * 4;
  #pragma unroll
  for (int ii = 0; ii < 4; ii++)
    #pragma unroll
    for (int jf = 0; jf < 2; jf++){
      int iW = it0 + jf*16 + (lane & 15);
      *(f32x4*)(out + (size_t)(b*256 + iW)*1024 + h*256 + oo0 + ii*16) = acc[ii][jf];
    }
}

extern "C" void kernel_launch(void* const* d_in, const int* in_sizes, int n_in,
                              void* d_out, int out_size, void* d_ws, size_t ws_size,
                              hipStream_t stream) {
  const float* atom   = (const float*)d_in[0];
  const float* x      = (const float*)d_in[1];
  const float* fc_w   = (const float*)d_in[2];
  const float* fc_b   = (const float*)d_in[3];
  const float* kers   = (const float*)d_in[4];
  const float* att_s  = (const float*)d_in[5];
  const float* att_n  = (const float*)d_in[6];
  const float* eps    = (const float*)d_in[7];
  const float* biases = (const float*)d_in[8];
  const float* att_b  = (const float*)d_in[9];

  // ws layout, 98.8 MiB total (ws_size >= 104 MiB established in R3).
  char* w = (char*)d_ws;
  short* WT      = (short*)(w);                      // 128 KB
  short* KhT     = (short*)(w + 131072);             // 512 KB
  float* diag    = (float*)(w + 655360);             // 128 KB
  float* a_s     = (float*)(w + 786432);             // 512 KB  [h][b][n]
  float* a_n     = (float*)(w + 1310720);            // 512 KB
  unsigned* xbits= (unsigned*)(w + 1835008);         // 1 MB
  short* atomG1  = (short*)(w + 2883584);            // 16 MB: atom_bf, then G1
  short* xbfF0   = (short*)(w + 19660800);           // 16 MB: x_bf, then featT[0]
  short* G2TF1   = (short*)(w + 36438016);           // 16 MB: G2T, then featT[1]
  short* G2nf    = (short*)(w + 53215232);           // 16 MB
  short* fT2     = (short*)(w + 69992448);           // 16 MB
  short* fT3     = (short*)(w + 86769664);           // 16 MB

  float* out  = (float*)d_out;
  float* out2 = out + 33554432;  // B*N*H*D floats

  ktrans<<<dim3(8, 8, 5), 256, 0, stream>>>(fc_w, kers, WT, KhT);
  kprep<<<dim3(8, 128, 2), 256, 0, stream>>>(atom, x, atomG1, xbfF0, xbits, diag);
  kG2<<<dim3(4, 128), 256, 0, stream>>>(WT, atomG1, G2TF1, G2nf);
  kG1<<<dim3(4, 128), 256, 0, stream>>>(G2TF1, xbfF0, atomG1);   // G1 overwrites atom_bf (dead)

  kFeatAll<<<dim3(2048), 256, 0, stream>>>(KhT, atomG1, G2nf, diag, fc_b, eps,
                                           biases, att_s, att_n,
                                           xbfF0, G2TF1, fT2, fT3, a_s, a_n);
  kAttnAll<<<dim3(4096), 256, 0, stream>>>(xbits, a_s, a_n, att_b,
                                           xbfF0, G2TF1, fT2, fT3, out, out2);
}

// Round 8
// 261.239 us; speedup vs baseline: 15.3244x; 1.0798x over previous
//
#include <hip/hip_runtime.h>

typedef __attribute__((ext_vector_type(8))) short bf16x8;
typedef __attribute__((ext_vector_type(4))) short short4v;
typedef __attribute__((ext_vector_type(4))) float f32x4;

// B=128, N=256, D=256, H=4 ; per-batch matrices are [256][256] (65536 elems)

__device__ __forceinline__ float b2f(short s){
  unsigned u = ((unsigned)(unsigned short)s) << 16;
  return __builtin_bit_cast(float, u);
}
__device__ __forceinline__ short f2b(float f){
  unsigned u = __builtin_bit_cast(unsigned, f);
  u = (u + 0x7FFFu + ((u >> 16) & 1u)) >> 16;
  return (short)(unsigned short)u;
}

// -------- transpose-convert f32 [256][256] -> bf16 ^T : z=0 fc_w->WT, z=1..4 kernels->KhT --------
__global__ __launch_bounds__(256) void ktrans(const float* __restrict__ fcw, const float* __restrict__ kers,
                                              short* __restrict__ WT, short* __restrict__ KhT){
  __shared__ float tile[32][33];
  int z = blockIdx.z;
  const float* src = (z == 0) ? fcw : (kers + (z-1)*65536);
  short* dst = (z == 0) ? WT : (KhT + (z-1)*65536);
  int x0 = blockIdx.x*32, y0 = blockIdx.y*32;
  int tx = threadIdx.x & 31, ty = threadIdx.x >> 5;
  #pragma unroll
  for (int i = 0; i < 32; i += 8) tile[ty+i][tx] = src[(y0+ty+i)*256 + x0+tx];
  __syncthreads();
  #pragma unroll
  for (int i = 0; i < 32; i += 8) dst[(x0+ty+i)*256 + y0+tx] = f2b(tile[tx][ty+i]);
}

// -------- prep: z=0 atom f32->bf16 ; z=1 x f32->bf16 + bitfields + diag. grid (8,128,2) --------
__global__ __launch_bounds__(256) void kprep(const float* __restrict__ atom, const float* __restrict__ x,
                                             short* __restrict__ atom_bf, short* __restrict__ xbf,
                                             unsigned* __restrict__ xbits, float* __restrict__ diag){
  int b = blockIdx.y;
  int row = blockIdx.x*32 + (threadIdx.x >> 3);
  int seg = threadIdx.x & 7;
  if (blockIdx.z == 0){
    const float* p = atom + b*65536 + row*256 + seg*32;
    short* q = atom_bf + b*65536 + row*256 + seg*32;
    #pragma unroll
    for (int k = 0; k < 4; k++){
      f32x4 a = ((const f32x4*)p)[k*2], c = ((const f32x4*)p)[k*2+1];
      bf16x8 o;
      #pragma unroll
      for (int e = 0; e < 4; e++){ o[e] = f2b(a[e]); o[4+e] = f2b(c[e]); }
      ((bf16x8*)q)[k] = o;
    }
  } else {
    const float* p = x + b*65536 + row*256 + seg*32;
    float v[32];
    #pragma unroll
    for (int k = 0; k < 8; k++){
      f32x4 qv = ((const f32x4*)p)[k];
      #pragma unroll
      for (int e = 0; e < 4; e++) v[k*4+e] = qv[e];
    }
    unsigned bits = 0u;
    #pragma unroll
    for (int e = 0; e < 32; e++) if (v[e] > 0.5f) bits |= (1u << e);
    xbits[(b*256 + row)*8 + seg] = bits;
    short* q = xbf + b*65536 + row*256 + seg*32;
    #pragma unroll
    for (int k = 0; k < 4; k++){
      bf16x8 o;
      #pragma unroll
      for (int e = 0; e < 8; e++) o[e] = f2b(v[k*8+e]);
      ((bf16x8*)q)[k] = o;
    }
    if ((row >> 5) == seg) diag[b*256 + row] = v[row & 31];
  }
}

// -------- G2 = atom @ W : G2T[f][m] (scalar) + G2nf[m][f] (vector C^T). grid (4,128) --------
__global__ __launch_bounds__(256) void kG2(const short* __restrict__ WT, const short* __restrict__ atomb,
                                           short* __restrict__ G2T, short* __restrict__ G2nf){
  int b = blockIdx.y;
  int tr = (blockIdx.x >> 1) * 128, tc = (blockIdx.x & 1) * 128;
  int lane = threadIdx.x & 63, wave = threadIdx.x >> 6;
  int wr = (wave >> 1) * 64, wc = (wave & 1) * 64;
  const short* Y = atomb + b * 65536;
  int r0 = tr + wr + (lane & 15);
  int c0 = tc + wc + (lane & 15);
  int koff = (lane >> 4) * 8;
  f32x4 acc[4][4] = {};
  for (int k0 = 0; k0 < 256; k0 += 32){
    bf16x8 af[4], bfr[4];
    #pragma unroll
    for (int i = 0; i < 4; i++) af[i]  = *(const bf16x8*)(WT + (r0 + i*16)*256 + k0 + koff);
    #pragma unroll
    for (int j = 0; j < 4; j++) bfr[j] = *(const bf16x8*)(Y  + (c0 + j*16)*256 + k0 + koff);
    #pragma unroll
    for (int i = 0; i < 4; i++)
      #pragma unroll
      for (int j = 0; j < 4; j++)
        acc[i][j] = __builtin_amdgcn_mfma_f32_16x16x32_bf16(af[i], bfr[j], acc[i][j], 0, 0, 0);
  }
  int fi0 = tr + wr + (lane >> 4) * 4;
  int mj0 = tc + wc + (lane & 15);
  #pragma unroll
  for (int i = 0; i < 4; i++)
    #pragma unroll
    for (int j = 0; j < 4; j++){
      short4v v;
      #pragma unroll
      for (int r = 0; r < 4; r++) v[r] = f2b(acc[i][j][r]);
      *(short4v*)(G2nf + b*65536 + (mj0 + j*16)*256 + fi0 + i*16) = v;   // [m][f]
      #pragma unroll
      for (int r = 0; r < 4; r++)
        G2T[b*65536 + (fi0 + i*16 + r)*256 + mj0 + j*16] = v[r];         // [f][m]
    }
}

// -------- G1 = x @ G2 : P(G2T, xbf), C^T store G1[n][f]. grid (4,128) --------
__global__ __launch_bounds__(256) void kG1(const short* __restrict__ G2T, const short* __restrict__ xbf,
                                           short* __restrict__ G1){
  int b = blockIdx.y;
  int tr = (blockIdx.x >> 1) * 128, tc = (blockIdx.x & 1) * 128;
  int lane = threadIdx.x & 63, wave = threadIdx.x >> 6;
  int wr = (wave >> 1) * 64, wc = (wave & 1) * 64;
  const short* X = G2T + b * 65536;
  const short* Y = xbf + b * 65536;
  int r0 = tr + wr + (lane & 15);
  int c0 = tc + wc + (lane & 15);
  int koff = (lane >> 4) * 8;
  f32x4 acc[4][4] = {};
  for (int k0 = 0; k0 < 256; k0 += 32){
    bf16x8 af[4], bfr[4];
    #pragma unroll
    for (int i = 0; i < 4; i++) af[i]  = *(const bf16x8*)(X + (r0 + i*16)*256 + k0 + koff);
    #pragma unroll
    for (int j = 0; j < 4; j++) bfr[j] = *(const bf16x8*)(Y + (c0 + j*16)*256 + k0 + koff);
    #pragma unroll
    for (int i = 0; i < 4; i++)
      #pragma unroll
      for (int j = 0; j < 4; j++)
        acc[i][j] = __builtin_amdgcn_mfma_f32_16x16x32_bf16(af[i], bfr[j], acc[i][j], 0, 0, 0);
  }
  int fi0 = tr + wr + (lane >> 4) * 4;
  int nj0 = tc + wc + (lane & 15);
  #pragma unroll
  for (int i = 0; i < 4; i++)
    #pragma unroll
    for (int j = 0; j < 4; j++){
      short4v v;
      #pragma unroll
      for (int r = 0; r < 4; r++) v[r] = f2b(acc[i][j][r]);
      *(short4v*)(G1 + b*65536 + (nj0 + j*16)*256 + fi0 + i*16) = v;     // [n][f]
    }
}

// -------- featT_h[o][n] = (h1_h @ K_h + bias)^T ; LDS-staged h1 rebuild; a_s/a_n in-block --------
// 1-D grid 1024, XCD-swizzled: the 8 blocks (4h x 2 n-halves) of batch b on xcd b%8.
// Block: 512 threads, 8 waves as 2(o)x4(n); wave tile 128o x 32n; output 256o x 128n.
__global__ __launch_bounds__(512, 4) void kFeatAll(const short* __restrict__ KhT, const short* __restrict__ G1,
                                                   const short* __restrict__ G2nf, const float* __restrict__ diag,
                                                   const float* __restrict__ fcb, const float* __restrict__ epsv,
                                                   const float* __restrict__ biases, const float* __restrict__ atts,
                                                   const float* __restrict__ attn,
                                                   short* __restrict__ fT0, short* __restrict__ fT1,
                                                   short* __restrict__ fT2, short* __restrict__ fT3,
                                                   float* __restrict__ a_s, float* __restrict__ a_n){
  __shared__ short h1s[128][40];     // [n-local][k] padded: 80B rows -> 16B-aligned, ~2-way banks
  __shared__ float red_s[8][32];
  __shared__ float red_n[8][32];
  int wg = blockIdx.x;                 // 0..1023
  int xcd = wg & 7;
  int idx = wg >> 3;                   // 0..127
  int b   = xcd + ((idx >> 3) << 3);   // 16 batches per xcd
  int sub = idx & 7;
  int h   = sub >> 1;
  int n0  = (sub & 1) * 128;
  int tid = threadIdx.x, lane = tid & 63, w = tid >> 6;
  short* featT = (h==0)?fT0:(h==1)?fT1:(h==2)?fT2:fT3;
  float epsm1 = epsv[h] - 1.0f;
  const short* KA = KhT + h*65536;
  const short* G1b = G1 + b*65536 + n0*256;
  const short* G2b = G2nf + b*65536 + n0*256;

  // rebuild assignment: thread -> (row 0..127, kk in {0,8,16,24})
  int rrow = tid >> 2;
  int rkk  = (tid & 3) * 8;
  float cj = epsm1 * diag[b*256 + n0 + rrow];

  // wave geometry
  int wro = (w >> 2) * 128;            // o-half
  int wn  = (w & 3) * 32;              // n-quarter (within 128)
  int lr = lane & 15, lq = lane >> 4;
  int koff = lq * 8;

  f32x4 acc[8][2] = {};
  for (int k0 = 0; k0 < 256; k0 += 32){
    // ---- cooperative rebuild of h1 tile [128n x 32k] into LDS
    {
      f32x4 f0 = *(const f32x4*)(fcb + k0 + rkk);
      f32x4 f1 = *(const f32x4*)(fcb + k0 + rkk + 4);
      bf16x8 g1 = *(const bf16x8*)(G1b + rrow*256 + k0 + rkk);
      bf16x8 g2 = *(const bf16x8*)(G2b + rrow*256 + k0 + rkk);
      bf16x8 o;
      #pragma unroll
      for (int e = 0; e < 8; e++){
        float fb = (e < 4) ? f0[e] : f1[e-4];
        float v = b2f(g1[e]) + cj*b2f(g2[e]) + fb;
        v = v > 0.f ? v : 0.01f*v;
        o[e] = f2b(v);
      }
      *(bf16x8*)&h1s[rrow][rkk] = o;
    }
    __syncthreads();
    // ---- MFMA: A direct from L2-hot KhT, B from LDS
    bf16x8 hb[2];
    #pragma unroll
    for (int j = 0; j < 2; j++) hb[j] = *(const bf16x8*)&h1s[wn + j*16 + lr][koff];
    #pragma unroll
    for (int i = 0; i < 8; i++){
      bf16x8 af = *(const bf16x8*)(KA + (wro + i*16 + lr)*256 + k0 + koff);
      acc[i][0] = __builtin_amdgcn_mfma_f32_16x16x32_bf16(af, hb[0], acc[i][0], 0, 0, 0);
      acc[i][1] = __builtin_amdgcn_mfma_f32_16x16x32_bf16(af, hb[1], acc[i][1], 0, 0, 0);
    }
    __syncthreads();
  }

  // ---- epilogue: bias add, featT store, a_s/a_n partial sums
  int c4 = lq * 4;
  float ps[2] = {0.f, 0.f}, pn[2] = {0.f, 0.f};
  #pragma unroll
  for (int i = 0; i < 8; i++){
    int ob = wro + i*16 + c4;
    f32x4 bi  = *(const f32x4*)(biases + h*256 + ob);
    f32x4 ws4 = *(const f32x4*)(atts   + h*256 + ob);
    f32x4 wn4 = *(const f32x4*)(attn   + h*256 + ob);
    #pragma unroll
    for (int r = 0; r < 4; r++){
      #pragma unroll
      for (int j = 0; j < 2; j++){
        int nn = n0 + wn + j*16 + lr;
        float fv = acc[i][j][r] + bi[r];
        featT[b*65536 + (ob + r)*256 + nn] = f2b(fv);
        ps[j] += fv * ws4[r];
        pn[j] += fv * wn4[r];
      }
    }
  }
  #pragma unroll
  for (int j = 0; j < 2; j++){
    float s = ps[j]; s += __shfl_xor(s, 16); s += __shfl_xor(s, 32);
    float nv = pn[j]; nv += __shfl_xor(nv, 16); nv += __shfl_xor(nv, 32);
    if (lane < 16){
      red_s[w][j*16 + lane] = s;
      red_n[w][j*16 + lane] = nv;
    }
  }
  __syncthreads();
  if (tid < 128){
    int g = tid >> 5;        // n-quarter
    int idx2 = tid & 31;
    float ss = red_s[g][idx2] + red_s[g+4][idx2];
    float nn = red_n[g][idx2] + red_n[g+4][idx2];
    a_s[(h*128 + b)*256 + n0 + tid] = ss;
    a_n[(h*128 + b)*256 + n0 + tid] = nn;
  }
}

// -------- softmax(elu(a_s+a_n)+mask) ; node = P @ feat ; f32 out ; att dump h==3 --------
// 1-D grid 4096, XCD-swizzled: the 8 i-tiles of group (h,b) share xcd b%8.
__global__ __launch_bounds__(256) void kAttnAll(const unsigned* __restrict__ xbits,
                                                const float* __restrict__ a_s, const float* __restrict__ a_n,
                                                const float* __restrict__ attbv,
                                                const short* __restrict__ fT0, const short* __restrict__ fT1,
                                                const short* __restrict__ fT2, const short* __restrict__ fT3,
                                                float* __restrict__ out, float* __restrict__ out2){
  __shared__ __align__(16) short Pbuf[32][264];
  int wg = blockIdx.x;                        // 0..4095
  int g  = (wg & 7) + ((wg >> 6) << 3);       // flat (h,b) group 0..511 ; xcd = g%8 = b%8
  int it0 = ((wg >> 3) & 7) * 32;
  int h = g >> 7, b = g & 127;
  int tid = threadIdx.x, lane = tid & 63, w = tid >> 6;
  const short* featT = (h==0)?fT0:(h==1)?fT1:(h==2)?fT2:fT3;
  const float* asp = a_s + (h*128 + b)*256;
  const float* anp = a_n + (h*128 + b)*256;

  // phase A: 32 rows x (8 segs x 32 cols)
  int row = tid >> 3, seg = tid & 7;
  int i = it0 + row;
  float asv = asp[i] + attbv[h];
  unsigned bits = xbits[(b*256 + i)*8 + seg];
  const f32x4* an4 = (const f32x4*)(anp + seg*32);
  float Lv[32];
  float mx = -3.0e38f;
  #pragma unroll
  for (int kk = 0; kk < 8; kk++){
    f32x4 a = an4[kk];
    #pragma unroll
    for (int e = 0; e < 4; e++){
      float s = asv + a[e];
      float el = s > 0.f ? s : (__expf(s) - 1.0f);
      float L = el + (((bits >> (kk*4+e)) & 1u) ? 0.f : -1.0e10f);
      Lv[kk*4+e] = L;
      mx = fmaxf(mx, L);
    }
  }
  mx = fmaxf(mx, __shfl_xor(mx, 1));
  mx = fmaxf(mx, __shfl_xor(mx, 2));
  mx = fmaxf(mx, __shfl_xor(mx, 4));
  float sum = 0.f;
  #pragma unroll
  for (int e = 0; e < 32; e++){ float p = __expf(Lv[e] - mx); Lv[e] = p; sum += p; }
  sum += __shfl_xor(sum, 1);
  sum += __shfl_xor(sum, 2);
  sum += __shfl_xor(sum, 4);
  float inv = 1.0f / sum;
  #pragma unroll
  for (int kk = 0; kk < 4; kk++){
    bf16x8 pv;
    #pragma unroll
    for (int e = 0; e < 8; e++) pv[e] = f2b(Lv[kk*8+e] * inv);
    *(bf16x8*)&Pbuf[row][seg*32 + kk*8] = pv;
  }
  if (h == 3){
    float* o2 = out2 + b*65536 + i*256 + seg*32;
    #pragma unroll
    for (int kk = 0; kk < 8; kk++){
      f32x4 v;
      #pragma unroll
      for (int e = 0; e < 4; e++) v[e] = Lv[kk*4+e] * inv;
      *(f32x4*)(o2 + kk*4) = v;
    }
  }
  __syncthreads();

  // phase B: nodeT = P(featT, Pbuf) ; C^T-write f32 to out
  int o0w = w * 64;
  const short* F = featT + b * 65536;
  int orow = o0w + (lane & 15);
  int koff = (lane >> 4) * 8;
  f32x4 acc[4][2] = {};
  for (int k0 = 0; k0 < 256; k0 += 32){
    bf16x8 af[4], bfr[2];
    #pragma unroll
    for (int ii = 0; ii < 4; ii++) af[ii] = *(const bf16x8*)(F + (orow + ii*16)*256 + k0 + koff);
    #pragma unroll
    for (int jf = 0; jf < 2; jf++) bfr[jf] = *(const bf16x8*)&Pbuf[jf*16 + (lane & 15)][k0 + koff];
    #pragma unroll
    for (int ii = 0; ii < 4; ii++)
      #pragma unroll
      for (int jf = 0; jf < 2; jf++)
        acc[ii][jf] = __builtin_amdgcn_mfma_f32_16x16x32_bf16(af[ii], bfr[jf], acc[ii][jf], 0, 0, 0);
  }
  int oo0 = o0w + (lane >> 4) * 4;
  #pragma unroll
  for (int ii = 0; ii < 4; ii++)
    #pragma unroll
    for (int jf = 0; jf < 2; jf++){
      int iW = it0 + jf*16 + (lane & 15);
      *(f32x4*)(out + (size_t)(b*256 + iW)*1024 + h*256 + oo0 + ii*16) = acc[ii][jf];
    }
}

extern "C" void kernel_launch(void* const* d_in, const int* in_sizes, int n_in,
                              void* d_out, int out_size, void* d_ws, size_t ws_size,
                              hipStream_t stream) {
  const float* atom   = (const float*)d_in[0];
  const float* x      = (const float*)d_in[1];
  const float* fc_w   = (const float*)d_in[2];
  const float* fc_b   = (const float*)d_in[3];
  const float* kers   = (const float*)d_in[4];
  const float* att_s  = (const float*)d_in[5];
  const float* att_n  = (const float*)d_in[6];
  const float* eps    = (const float*)d_in[7];
  const float* biases = (const float*)d_in[8];
  const float* att_b  = (const float*)d_in[9];

  // ws layout, 98.8 MiB total (ws_size >= 104 MiB established in R3).
  char* w = (char*)d_ws;
  short* WT      = (short*)(w);                      // 128 KB
  short* KhT     = (short*)(w + 131072);             // 512 KB
  float* diag    = (float*)(w + 655360);             // 128 KB
  float* a_s     = (float*)(w + 786432);             // 512 KB  [h][b][n]
  float* a_n     = (float*)(w + 1310720);            // 512 KB
  unsigned* xbits= (unsigned*)(w + 1835008);         // 1 MB
  short* atomG1  = (short*)(w + 2883584);            // 16 MB: atom_bf, then G1
  short* xbfF0   = (short*)(w + 19660800);           // 16 MB: x_bf, then featT[0]
  short* G2TF1   = (short*)(w + 36438016);           // 16 MB: G2T, then featT[1]
  short* G2nf    = (short*)(w + 53215232);           // 16 MB
  short* fT2     = (short*)(w + 69992448);           // 16 MB
  short* fT3     = (short*)(w + 86769664);           // 16 MB

  float* out  = (float*)d_out;
  float* out2 = out + 33554432;  // B*N*H*D floats

  ktrans<<<dim3(8, 8, 5), 256, 0, stream>>>(fc_w, kers, WT, KhT);
  kprep<<<dim3(8, 128, 2), 256, 0, stream>>>(atom, x, atomG1, xbfF0, xbits, diag);
  kG2<<<dim3(4, 128), 256, 0, stream>>>(WT, atomG1, G2TF1, G2nf);
  kG1<<<dim3(4, 128), 256, 0, stream>>>(G2TF1, xbfF0, atomG1);   // G1 overwrites atom_bf (dead)

  kFeatAll<<<dim3(1024), 512, 0, stream>>>(KhT, atomG1, G2nf, diag, fc_b, eps,
                                           biases, att_s, att_n,
                                           xbfF0, G2TF1, fT2, fT3, a_s, a_n);
  kAttnAll<<<dim3(4096), 256, 0, stream>>>(xbits, a_s, a_n, att_b,
                                           xbfF0, G2TF1, fT2, fT3, out, out2);
}

// Round 9
// 206.726 us; speedup vs baseline: 19.3653x; 1.2637x over previous
//
#include <hip/hip_runtime.h>

typedef __attribute__((ext_vector_type(8))) short bf16x8;
typedef __attribute__((ext_vector_type(4))) short short4v;
typedef __attribute__((ext_vector_type(4))) float f32x4;

// B=128, N=256, D=256, H=4 ; per-batch matrices are [256][256] (65536 elems)

__device__ __forceinline__ float b2f(short s){
  unsigned u = ((unsigned)(unsigned short)s) << 16;
  return __builtin_bit_cast(float, u);
}
__device__ __forceinline__ short f2b(float f){
  unsigned u = __builtin_bit_cast(unsigned, f);
  u = (u + 0x7FFFu + ((u >> 16) & 1u)) >> 16;
  return (short)(unsigned short)u;
}

// -------- transpose-convert f32 [256][256] -> bf16 ^T : z=0 fc_w->WT, z=1..4 kernels->KhT --------
__global__ __launch_bounds__(256) void ktrans(const float* __restrict__ fcw, const float* __restrict__ kers,
                                              short* __restrict__ WT, short* __restrict__ KhT){
  __shared__ float tile[32][33];
  int z = blockIdx.z;
  const float* src = (z == 0) ? fcw : (kers + (z-1)*65536);
  short* dst = (z == 0) ? WT : (KhT + (z-1)*65536);
  int x0 = blockIdx.x*32, y0 = blockIdx.y*32;
  int tx = threadIdx.x & 31, ty = threadIdx.x >> 5;
  #pragma unroll
  for (int i = 0; i < 32; i += 8) tile[ty+i][tx] = src[(y0+ty+i)*256 + x0+tx];
  __syncthreads();
  #pragma unroll
  for (int i = 0; i < 32; i += 8) dst[(x0+ty+i)*256 + y0+tx] = f2b(tile[tx][ty+i]);
}

// -------- prep: z=0 atom f32->bf16 ; z=1 x f32->bf16 + bitfields + diag. grid (8,128,2) --------
__global__ __launch_bounds__(256) void kprep(const float* __restrict__ atom, const float* __restrict__ x,
                                             short* __restrict__ atom_bf, short* __restrict__ xbf,
                                             unsigned* __restrict__ xbits, float* __restrict__ diag){
  int b = blockIdx.y;
  int row = blockIdx.x*32 + (threadIdx.x >> 3);
  int seg = threadIdx.x & 7;
  if (blockIdx.z == 0){
    const float* p = atom + b*65536 + row*256 + seg*32;
    short* q = atom_bf + b*65536 + row*256 + seg*32;
    #pragma unroll
    for (int k = 0; k < 4; k++){
      f32x4 a = ((const f32x4*)p)[k*2], c = ((const f32x4*)p)[k*2+1];
      bf16x8 o;
      #pragma unroll
      for (int e = 0; e < 4; e++){ o[e] = f2b(a[e]); o[4+e] = f2b(c[e]); }
      ((bf16x8*)q)[k] = o;
    }
  } else {
    const float* p = x + b*65536 + row*256 + seg*32;
    float v[32];
    #pragma unroll
    for (int k = 0; k < 8; k++){
      f32x4 qv = ((const f32x4*)p)[k];
      #pragma unroll
      for (int e = 0; e < 4; e++) v[k*4+e] = qv[e];
    }
    unsigned bits = 0u;
    #pragma unroll
    for (int e = 0; e < 32; e++) if (v[e] > 0.5f) bits |= (1u << e);
    xbits[(b*256 + row)*8 + seg] = bits;
    short* q = xbf + b*65536 + row*256 + seg*32;
    #pragma unroll
    for (int k = 0; k < 4; k++){
      bf16x8 o;
      #pragma unroll
      for (int e = 0; e < 8; e++) o[e] = f2b(v[k*8+e]);
      ((bf16x8*)q)[k] = o;
    }
    if ((row >> 5) == seg) diag[b*256 + row] = v[row & 31];
  }
}

// -------- G2 = atom @ W : G2T[f][m] (scalar) + G2nf[m][f] (vector C^T). grid (4,128) --------
__global__ __launch_bounds__(256) void kG2(const short* __restrict__ WT, const short* __restrict__ atomb,
                                           short* __restrict__ G2T, short* __restrict__ G2nf){
  int b = blockIdx.y;
  int tr = (blockIdx.x >> 1) * 128, tc = (blockIdx.x & 1) * 128;
  int lane = threadIdx.x & 63, wave = threadIdx.x >> 6;
  int wr = (wave >> 1) * 64, wc = (wave & 1) * 64;
  const short* Y = atomb + b * 65536;
  int r0 = tr + wr + (lane & 15);
  int c0 = tc + wc + (lane & 15);
  int koff = (lane >> 4) * 8;
  f32x4 acc[4][4] = {};
  for (int k0 = 0; k0 < 256; k0 += 32){
    bf16x8 af[4], bfr[4];
    #pragma unroll
    for (int i = 0; i < 4; i++) af[i]  = *(const bf16x8*)(WT + (r0 + i*16)*256 + k0 + koff);
    #pragma unroll
    for (int j = 0; j < 4; j++) bfr[j] = *(const bf16x8*)(Y  + (c0 + j*16)*256 + k0 + koff);
    #pragma unroll
    for (int i = 0; i < 4; i++)
      #pragma unroll
      for (int j = 0; j < 4; j++)
        acc[i][j] = __builtin_amdgcn_mfma_f32_16x16x32_bf16(af[i], bfr[j], acc[i][j], 0, 0, 0);
  }
  int fi0 = tr + wr + (lane >> 4) * 4;
  int mj0 = tc + wc + (lane & 15);
  #pragma unroll
  for (int i = 0; i < 4; i++)
    #pragma unroll
    for (int j = 0; j < 4; j++){
      short4v v;
      #pragma unroll
      for (int r = 0; r < 4; r++) v[r] = f2b(acc[i][j][r]);
      *(short4v*)(G2nf + b*65536 + (mj0 + j*16)*256 + fi0 + i*16) = v;   // [m][f]
      #pragma unroll
      for (int r = 0; r < 4; r++)
        G2T[b*65536 + (fi0 + i*16 + r)*256 + mj0 + j*16] = v[r];         // [f][m]
    }
}

// -------- G1 = x @ G2 : P(G2T, xbf), C^T store G1[n][f]. grid (4,128) --------
__global__ __launch_bounds__(256) void kG1(const short* __restrict__ G2T, const short* __restrict__ xbf,
                                           short* __restrict__ G1){
  int b = blockIdx.y;
  int tr = (blockIdx.x >> 1) * 128, tc = (blockIdx.x & 1) * 128;
  int lane = threadIdx.x & 63, wave = threadIdx.x >> 6;
  int wr = (wave >> 1) * 64, wc = (wave & 1) * 64;
  const short* X = G2T + b * 65536;
  const short* Y = xbf + b * 65536;
  int r0 = tr + wr + (lane & 15);
  int c0 = tc + wc + (lane & 15);
  int koff = (lane >> 4) * 8;
  f32x4 acc[4][4] = {};
  for (int k0 = 0; k0 < 256; k0 += 32){
    bf16x8 af[4], bfr[4];
    #pragma unroll
    for (int i = 0; i < 4; i++) af[i]  = *(const bf16x8*)(X + (r0 + i*16)*256 + k0 + koff);
    #pragma unroll
    for (int j = 0; j < 4; j++) bfr[j] = *(const bf16x8*)(Y + (c0 + j*16)*256 + k0 + koff);
    #pragma unroll
    for (int i = 0; i < 4; i++)
      #pragma unroll
      for (int j = 0; j < 4; j++)
        acc[i][j] = __builtin_amdgcn_mfma_f32_16x16x32_bf16(af[i], bfr[j], acc[i][j], 0, 0, 0);
  }
  int fi0 = tr + wr + (lane >> 4) * 4;
  int nj0 = tc + wc + (lane & 15);
  #pragma unroll
  for (int i = 0; i < 4; i++)
    #pragma unroll
    for (int j = 0; j < 4; j++){
      short4v v;
      #pragma unroll
      for (int r = 0; r < 4; r++) v[r] = f2b(acc[i][j][r]);
      *(short4v*)(G1 + b*65536 + (nj0 + j*16)*256 + fi0 + i*16) = v;     // [n][f]
    }
}

// ======== kHead: per (h,b) block — feat GEMM into LDS, then softmax+PV from LDS ========
// grid 512, 512 threads (8 waves). XCD-swizzle: 4 heads of batch b adjacent, xcd = b%8.
// Phase 1: feat[o][n] (256x256): waves 2(o)x4(n), wave 128o x 64n; h1 rebuilt to LDS per K-step.
// Phase 2: 8 passes of 32 i-rows: softmax(tid<256) -> Pbuf ; PV: waves split o (32 each).
__global__ __launch_bounds__(512, 1) void kHead(const short* __restrict__ KhT, const short* __restrict__ G1,
                                                const short* __restrict__ G2nf, const float* __restrict__ diag,
                                                const float* __restrict__ fcb, const float* __restrict__ epsv,
                                                const float* __restrict__ biases, const float* __restrict__ atts,
                                                const float* __restrict__ attn,
                                                const unsigned* __restrict__ xbits, const float* __restrict__ attbv,
                                                float* __restrict__ out, float* __restrict__ out2){
  __shared__ __align__(16) short featS[256][264];   // 135168 B: feat[o][n] bf16
  __shared__ __align__(16) char scratch[20480];     // h1s | {red_s,red_n} | Pbuf (disjoint lifetimes)
  __shared__ float asv[256], anv[256];

  short (*h1s)[40]  = (short(*)[40])scratch;        // [256 n][32 k padded]
  float (*red_s)[64] = (float(*)[64])scratch;       // [8][64]
  float (*red_n)[64] = (float(*)[64])(scratch + 2048);
  short (*Pbuf)[264] = (short(*)[264])scratch;      // [32][264]

  int wg = blockIdx.x;              // 0..511
  int xcd = wg & 7;
  int idx = wg >> 3;                // 0..63
  int b = xcd + ((idx >> 2) << 3);  // 16 batches per xcd, 4 heads adjacent
  int h = idx & 3;
  int tid = threadIdx.x, lane = tid & 63, w = tid >> 6;

  float epsm1 = epsv[h] - 1.0f;
  float attb  = attbv[h];
  const short* KA  = KhT + h*65536;
  const short* G1b = G1  + b*65536;
  const short* G2b = G2nf + b*65536;

  // rebuild assignment: thread -> (row 0..255, 16-k half)
  int rrow = tid >> 1, rkk = (tid & 1) * 16;
  float cj = epsm1 * diag[b*256 + rrow];

  // wave geometry (phase 1)
  int wro = (w >> 2) * 128;         // o-half
  int wn  = (w & 3) * 64;           // n-quarter
  int lr = lane & 15, lq = lane >> 4;
  int koff = lq * 8;

  // ---------------- phase 1: feat = h1 @ K_h ----------------
  f32x4 acc[8][4] = {};
  for (int k0 = 0; k0 < 256; k0 += 32){
    // cooperative h1 rebuild: [256 n][32 k] -> LDS
    #pragma unroll
    for (int q = 0; q < 2; q++){
      int kk = rkk + q*8;
      f32x4 f0 = *(const f32x4*)(fcb + k0 + kk);
      f32x4 f1 = *(const f32x4*)(fcb + k0 + kk + 4);
      bf16x8 g1 = *(const bf16x8*)(G1b + rrow*256 + k0 + kk);
      bf16x8 g2 = *(const bf16x8*)(G2b + rrow*256 + k0 + kk);
      bf16x8 o;
      #pragma unroll
      for (int e = 0; e < 8; e++){
        float fb = (e < 4) ? f0[e] : f1[e-4];
        float v = b2f(g1[e]) + cj*b2f(g2[e]) + fb;
        v = v > 0.f ? v : 0.01f*v;
        o[e] = f2b(v);
      }
      *(bf16x8*)&h1s[rrow][kk] = o;
    }
    __syncthreads();
    bf16x8 hb[4];
    #pragma unroll
    for (int j = 0; j < 4; j++) hb[j] = *(const bf16x8*)&h1s[wn + j*16 + lr][koff];
    #pragma unroll
    for (int i = 0; i < 8; i++){
      bf16x8 af = *(const bf16x8*)(KA + (wro + i*16 + lr)*256 + k0 + koff);
      #pragma unroll
      for (int j = 0; j < 4; j++)
        acc[i][j] = __builtin_amdgcn_mfma_f32_16x16x32_bf16(af, hb[j], acc[i][j], 0, 0, 0);
    }
    __syncthreads();
  }

  // ---------------- epilogue 1: bias, featS store, a_s/a_n partials ----------------
  int c4 = lq * 4;
  float ps[4] = {0.f,0.f,0.f,0.f}, pn[4] = {0.f,0.f,0.f,0.f};
  #pragma unroll
  for (int i = 0; i < 8; i++){
    int ob = wro + i*16 + c4;
    f32x4 bi  = *(const f32x4*)(biases + h*256 + ob);
    f32x4 ws4 = *(const f32x4*)(atts   + h*256 + ob);
    f32x4 wn4 = *(const f32x4*)(attn   + h*256 + ob);
    #pragma unroll
    for (int r = 0; r < 4; r++){
      #pragma unroll
      for (int j = 0; j < 4; j++){
        int nn = wn + j*16 + lr;
        float fv = acc[i][j][r] + bi[r];
        featS[ob + r][nn] = f2b(fv);
        ps[j] += fv * ws4[r];
        pn[j] += fv * wn4[r];
      }
    }
  }
  // reduce over o: lanes differing in lq (bits 4-5), then waves w and w+4
  #pragma unroll
  for (int j = 0; j < 4; j++){
    float s = ps[j]; s += __shfl_xor(s, 16); s += __shfl_xor(s, 32);
    float nv = pn[j]; nv += __shfl_xor(nv, 16); nv += __shfl_xor(nv, 32);
    if (lane < 16){
      red_s[w][j*16 + lane] = s;
      red_n[w][j*16 + lane] = nv;
    }
  }
  __syncthreads();
  if (tid < 256){
    int wq = tid >> 6, ln = tid & 63;
    asv[tid] = red_s[wq][ln] + red_s[wq+4][ln] + attb;
    anv[tid] = red_n[wq][ln] + red_n[wq+4][ln];
  }
  __syncthreads();

  // ---------------- phase 2: 8 passes of 32 i-rows ----------------
  for (int it0 = 0; it0 < 256; it0 += 32){
    // phase A: softmax (first 4 waves)
    if (tid < 256){
      int row = tid >> 3, seg = tid & 7;
      int i = it0 + row;
      float as_i = asv[i];
      unsigned bits = xbits[(b*256 + i)*8 + seg];
      float Lv[32];
      float mx = -3.0e38f;
      #pragma unroll
      for (int kk = 0; kk < 8; kk++){
        #pragma unroll
        for (int e = 0; e < 4; e++){
          float s = as_i + anv[seg*32 + kk*4 + e];
          float el = s > 0.f ? s : (__expf(s) - 1.0f);
          float L = el + (((bits >> (kk*4+e)) & 1u) ? 0.f : -1.0e10f);
          Lv[kk*4+e] = L;
          mx = fmaxf(mx, L);
        }
      }
      mx = fmaxf(mx, __shfl_xor(mx, 1));
      mx = fmaxf(mx, __shfl_xor(mx, 2));
      mx = fmaxf(mx, __shfl_xor(mx, 4));
      float sum = 0.f;
      #pragma unroll
      for (int e = 0; e < 32; e++){ float p = __expf(Lv[e] - mx); Lv[e] = p; sum += p; }
      sum += __shfl_xor(sum, 1);
      sum += __shfl_xor(sum, 2);
      sum += __shfl_xor(sum, 4);
      float inv = 1.0f / sum;
      #pragma unroll
      for (int kk = 0; kk < 4; kk++){
        bf16x8 pv;
        #pragma unroll
        for (int e = 0; e < 8; e++) pv[e] = f2b(Lv[kk*8+e] * inv);
        *(bf16x8*)&Pbuf[row][seg*32 + kk*8] = pv;
      }
      if (h == 3){
        float* o2 = out2 + b*65536 + i*256 + seg*32;
        #pragma unroll
        for (int kk = 0; kk < 8; kk++){
          f32x4 v;
          #pragma unroll
          for (int e = 0; e < 4; e++) v[e] = Lv[kk*4+e] * inv;
          *(f32x4*)(o2 + kk*4) = v;
        }
      }
    }
    __syncthreads();

    // phase B: nodeT tile = P(featS rows, Pbuf) ; wave owns 32 o-rows
    f32x4 acc2[2][2] = {};
    int o0w = w * 32;
    for (int k0 = 0; k0 < 256; k0 += 32){
      bf16x8 af[2], bfr[2];
      #pragma unroll
      for (int ii = 0; ii < 2; ii++) af[ii] = *(const bf16x8*)&featS[o0w + ii*16 + lr][k0 + koff];
      #pragma unroll
      for (int jf = 0; jf < 2; jf++) bfr[jf] = *(const bf16x8*)&Pbuf[jf*16 + lr][k0 + koff];
      #pragma unroll
      for (int ii = 0; ii < 2; ii++)
        #pragma unroll
        for (int jf = 0; jf < 2; jf++)
          acc2[ii][jf] = __builtin_amdgcn_mfma_f32_16x16x32_bf16(af[ii], bfr[jf], acc2[ii][jf], 0, 0, 0);
    }
    #pragma unroll
    for (int ii = 0; ii < 2; ii++)
      #pragma unroll
      for (int jf = 0; jf < 2; jf++){
        int iW = it0 + jf*16 + lr;
        *(f32x4*)(out + (size_t)(b*256 + iW)*1024 + h*256 + o0w + ii*16 + c4) = acc2[ii][jf];
      }
    __syncthreads();
  }
}

extern "C" void kernel_launch(void* const* d_in, const int* in_sizes, int n_in,
                              void* d_out, int out_size, void* d_ws, size_t ws_size,
                              hipStream_t stream) {
  const float* atom   = (const float*)d_in[0];
  const float* x      = (const float*)d_in[1];
  const float* fc_w   = (const float*)d_in[2];
  const float* fc_b   = (const float*)d_in[3];
  const float* kers   = (const float*)d_in[4];
  const float* att_s  = (const float*)d_in[5];
  const float* att_n  = (const float*)d_in[6];
  const float* eps    = (const float*)d_in[7];
  const float* biases = (const float*)d_in[8];
  const float* att_b  = (const float*)d_in[9];

  // ws layout (~67 MB)
  char* w = (char*)d_ws;
  short* WT      = (short*)(w);                      // 128 KB
  short* KhT     = (short*)(w + 131072);             // 512 KB
  float* diag    = (float*)(w + 655360);             // 128 KB
  unsigned* xbits= (unsigned*)(w + 786432);          // 1 MB
  short* atomG1  = (short*)(w + 1835008);            // 16 MB: atom_bf, then G1
  short* xbf     = (short*)(w + 18612224);           // 16 MB
  short* G2T     = (short*)(w + 35389440);           // 16 MB
  short* G2nf    = (short*)(w + 52166656);           // 16 MB

  float* out  = (float*)d_out;
  float* out2 = out + 33554432;  // B*N*H*D floats

  ktrans<<<dim3(8, 8, 5), 256, 0, stream>>>(fc_w, kers, WT, KhT);
  kprep<<<dim3(8, 128, 2), 256, 0, stream>>>(atom, x, atomG1, xbf, xbits, diag);
  kG2<<<dim3(4, 128), 256, 0, stream>>>(WT, atomG1, G2T, G2nf);
  kG1<<<dim3(4, 128), 256, 0, stream>>>(G2T, xbf, atomG1);   // G1 overwrites atom_bf (dead)

  kHead<<<dim3(512), 512, 0, stream>>>(KhT, atomG1, G2nf, diag, fc_b, eps,
                                       biases, att_s, att_n, xbits, att_b, out, out2);
}

// Round 10
// 195.946 us; speedup vs baseline: 20.4307x; 1.0550x over previous
//
#include <hip/hip_runtime.h>

typedef __attribute__((ext_vector_type(8))) short bf16x8;
typedef __attribute__((ext_vector_type(4))) short short4v;
typedef __attribute__((ext_vector_type(4))) float f32x4;

// B=128, N=256, D=256, H=4 ; per-batch matrices are [256][256] (65536 elems)

__device__ __forceinline__ float b2f(short s){
  unsigned u = ((unsigned)(unsigned short)s) << 16;
  return __builtin_bit_cast(float, u);
}
__device__ __forceinline__ short f2b(float f){
  unsigned u = __builtin_bit_cast(unsigned, f);
  u = (u + 0x7FFFu + ((u >> 16) & 1u)) >> 16;
  return (short)(unsigned short)u;
}

// XOR swizzle: spread rows (stride 512 B) across the 8 16B-slot orbit -> all 32 banks used.
#define SWZ(row, bytecol) ((((row) * 512) + (bytecol)) ^ (((row) & 7) << 4))

// -------- transpose-convert f32 [256][256] -> bf16 ^T : z=0 fc_w->WT, z=1..4 kernels->KhT --------
__global__ __launch_bounds__(256) void ktrans(const float* __restrict__ fcw, const float* __restrict__ kers,
                                              short* __restrict__ WT, short* __restrict__ KhT){
  __shared__ float tile[32][33];
  int z = blockIdx.z;
  const float* src = (z == 0) ? fcw : (kers + (z-1)*65536);
  short* dst = (z == 0) ? WT : (KhT + (z-1)*65536);
  int x0 = blockIdx.x*32, y0 = blockIdx.y*32;
  int tx = threadIdx.x & 31, ty = threadIdx.x >> 5;
  #pragma unroll
  for (int i = 0; i < 32; i += 8) tile[ty+i][tx] = src[(y0+ty+i)*256 + x0+tx];
  __syncthreads();
  #pragma unroll
  for (int i = 0; i < 32; i += 8) dst[(x0+ty+i)*256 + y0+tx] = f2b(tile[tx][ty+i]);
}

// -------- prep: z=0 atom f32->bf16 ; z=1 x f32->bf16 + bitfields + diag. grid (8,128,2) --------
__global__ __launch_bounds__(256) void kprep(const float* __restrict__ atom, const float* __restrict__ x,
                                             short* __restrict__ atom_bf, short* __restrict__ xbf,
                                             unsigned* __restrict__ xbits, float* __restrict__ diag){
  int b = blockIdx.y;
  int row = blockIdx.x*32 + (threadIdx.x >> 3);
  int seg = threadIdx.x & 7;
  if (blockIdx.z == 0){
    const float* p = atom + b*65536 + row*256 + seg*32;
    short* q = atom_bf + b*65536 + row*256 + seg*32;
    #pragma unroll
    for (int k = 0; k < 4; k++){
      f32x4 a = ((const f32x4*)p)[k*2], c = ((const f32x4*)p)[k*2+1];
      bf16x8 o;
      #pragma unroll
      for (int e = 0; e < 4; e++){ o[e] = f2b(a[e]); o[4+e] = f2b(c[e]); }
      ((bf16x8*)q)[k] = o;
    }
  } else {
    const float* p = x + b*65536 + row*256 + seg*32;
    float v[32];
    #pragma unroll
    for (int k = 0; k < 8; k++){
      f32x4 qv = ((const f32x4*)p)[k];
      #pragma unroll
      for (int e = 0; e < 4; e++) v[k*4+e] = qv[e];
    }
    unsigned bits = 0u;
    #pragma unroll
    for (int e = 0; e < 32; e++) if (v[e] > 0.5f) bits |= (1u << e);
    xbits[(b*256 + row)*8 + seg] = bits;
    short* q = xbf + b*65536 + row*256 + seg*32;
    #pragma unroll
    for (int k = 0; k < 4; k++){
      bf16x8 o;
      #pragma unroll
      for (int e = 0; e < 8; e++) o[e] = f2b(v[k*8+e]);
      ((bf16x8*)q)[k] = o;
    }
    if ((row >> 5) == seg) diag[b*256 + row] = v[row & 31];
  }
}

// -------- G2 = atom @ W : G2T[f][m] (scalar) + G2nf[m][f] (vector C^T). grid (4,128) --------
__global__ __launch_bounds__(256) void kG2(const short* __restrict__ WT, const short* __restrict__ atomb,
                                           short* __restrict__ G2T, short* __restrict__ G2nf){
  int b = blockIdx.y;
  int tr = (blockIdx.x >> 1) * 128, tc = (blockIdx.x & 1) * 128;
  int lane = threadIdx.x & 63, wave = threadIdx.x >> 6;
  int wr = (wave >> 1) * 64, wc = (wave & 1) * 64;
  const short* Y = atomb + b * 65536;
  int r0 = tr + wr + (lane & 15);
  int c0 = tc + wc + (lane & 15);
  int koff = (lane >> 4) * 8;
  f32x4 acc[4][4] = {};
  for (int k0 = 0; k0 < 256; k0 += 32){
    bf16x8 af[4], bfr[4];
    #pragma unroll
    for (int i = 0; i < 4; i++) af[i]  = *(const bf16x8*)(WT + (r0 + i*16)*256 + k0 + koff);
    #pragma unroll
    for (int j = 0; j < 4; j++) bfr[j] = *(const bf16x8*)(Y  + (c0 + j*16)*256 + k0 + koff);
    #pragma unroll
    for (int i = 0; i < 4; i++)
      #pragma unroll
      for (int j = 0; j < 4; j++)
        acc[i][j] = __builtin_amdgcn_mfma_f32_16x16x32_bf16(af[i], bfr[j], acc[i][j], 0, 0, 0);
  }
  int fi0 = tr + wr + (lane >> 4) * 4;
  int mj0 = tc + wc + (lane & 15);
  #pragma unroll
  for (int i = 0; i < 4; i++)
    #pragma unroll
    for (int j = 0; j < 4; j++){
      short4v v;
      #pragma unroll
      for (int r = 0; r < 4; r++) v[r] = f2b(acc[i][j][r]);
      *(short4v*)(G2nf + b*65536 + (mj0 + j*16)*256 + fi0 + i*16) = v;   // [m][f]
      #pragma unroll
      for (int r = 0; r < 4; r++)
        G2T[b*65536 + (fi0 + i*16 + r)*256 + mj0 + j*16] = v[r];         // [f][m]
    }
}

// -------- G1 = x @ G2 : P(G2T, xbf), C^T store G1[n][f]. grid (4,128) --------
__global__ __launch_bounds__(256) void kG1(const short* __restrict__ G2T, const short* __restrict__ xbf,
                                           short* __restrict__ G1){
  int b = blockIdx.y;
  int tr = (blockIdx.x >> 1) * 128, tc = (blockIdx.x & 1) * 128;
  int lane = threadIdx.x & 63, wave = threadIdx.x >> 6;
  int wr = (wave >> 1) * 64, wc = (wave & 1) * 64;
  const short* X = G2T + b * 65536;
  const short* Y = xbf + b * 65536;
  int r0 = tr + wr + (lane & 15);
  int c0 = tc + wc + (lane & 15);
  int koff = (lane >> 4) * 8;
  f32x4 acc[4][4] = {};
  for (int k0 = 0; k0 < 256; k0 += 32){
    bf16x8 af[4], bfr[4];
    #pragma unroll
    for (int i = 0; i < 4; i++) af[i]  = *(const bf16x8*)(X + (r0 + i*16)*256 + k0 + koff);
    #pragma unroll
    for (int j = 0; j < 4; j++) bfr[j] = *(const bf16x8*)(Y + (c0 + j*16)*256 + k0 + koff);
    #pragma unroll
    for (int i = 0; i < 4; i++)
      #pragma unroll
      for (int j = 0; j < 4; j++)
        acc[i][j] = __builtin_amdgcn_mfma_f32_16x16x32_bf16(af[i], bfr[j], acc[i][j], 0, 0, 0);
  }
  int fi0 = tr + wr + (lane >> 4) * 4;
  int nj0 = tc + wc + (lane & 15);
  #pragma unroll
  for (int i = 0; i < 4; i++)
    #pragma unroll
    for (int j = 0; j < 4; j++){
      short4v v;
      #pragma unroll
      for (int r = 0; r < 4; r++) v[r] = f2b(acc[i][j][r]);
      *(short4v*)(G1 + b*65536 + (nj0 + j*16)*256 + fi0 + i*16) = v;     // [n][f]
    }
}

// ======== kHead: per (h,b) block — feat GEMM into LDS, then softmax+PV from LDS ========
// grid 512, 512 threads (8 waves). XCD-swizzle: 4 heads of batch b adjacent, xcd = b%8.
// featS/Pbuf XOR-swizzled (SWZ) to kill 8-way bank conflicts on phase-B b128 reads.
__global__ __launch_bounds__(512, 1) void kHead(const short* __restrict__ KhT, const short* __restrict__ G1,
                                                const short* __restrict__ G2nf, const float* __restrict__ diag,
                                                const float* __restrict__ fcb, const float* __restrict__ epsv,
                                                const float* __restrict__ biases, const float* __restrict__ atts,
                                                const float* __restrict__ attn,
                                                const unsigned* __restrict__ xbits, const float* __restrict__ attbv,
                                                float* __restrict__ out, float* __restrict__ out2){
  __shared__ __align__(16) char featS[131072];      // feat[o][n] bf16, SWZ-swizzled
  __shared__ __align__(16) char scratch[20480];     // h1s | {red_s,red_n} | Pbuf (disjoint lifetimes)
  __shared__ float asv[256], anv[256];

  short (*h1s)[40]  = (short(*)[40])scratch;        // [256 n][32 k padded]
  float (*red_s)[64] = (float(*)[64])scratch;       // [8][64]
  float (*red_n)[64] = (float(*)[64])(scratch + 2048);
  char* Pbuf = scratch;                             // [32][256] bf16, SWZ-swizzled

  int wg = blockIdx.x;              // 0..511
  int xcd = wg & 7;
  int idx = wg >> 3;                // 0..63
  int b = xcd + ((idx >> 2) << 3);  // 16 batches per xcd, 4 heads adjacent
  int h = idx & 3;
  int tid = threadIdx.x, lane = tid & 63, w = tid >> 6;

  float epsm1 = epsv[h] - 1.0f;
  float attb  = attbv[h];
  const short* KA  = KhT + h*65536;
  const short* G1b = G1  + b*65536;
  const short* G2b = G2nf + b*65536;

  // rebuild assignment: thread -> (row 0..255, 16-k half)
  int rrow = tid >> 1, rkk = (tid & 1) * 16;
  float cj = epsm1 * diag[b*256 + rrow];

  // wave geometry (phase 1)
  int wro = (w >> 2) * 128;         // o-half
  int wn  = (w & 3) * 64;           // n-quarter
  int lr = lane & 15, lq = lane >> 4;
  int koff = lq * 8;

  // ---------------- phase 1: feat = h1 @ K_h ----------------
  f32x4 acc[8][4] = {};
  for (int k0 = 0; k0 < 256; k0 += 32){
    // cooperative h1 rebuild: [256 n][32 k] -> LDS
    #pragma unroll
    for (int q = 0; q < 2; q++){
      int kk = rkk + q*8;
      f32x4 f0 = *(const f32x4*)(fcb + k0 + kk);
      f32x4 f1 = *(const f32x4*)(fcb + k0 + kk + 4);
      bf16x8 g1 = *(const bf16x8*)(G1b + rrow*256 + k0 + kk);
      bf16x8 g2 = *(const bf16x8*)(G2b + rrow*256 + k0 + kk);
      bf16x8 o;
      #pragma unroll
      for (int e = 0; e < 8; e++){
        float fb = (e < 4) ? f0[e] : f1[e-4];
        float v = b2f(g1[e]) + cj*b2f(g2[e]) + fb;
        v = v > 0.f ? v : 0.01f*v;
        o[e] = f2b(v);
      }
      *(bf16x8*)&h1s[rrow][kk] = o;
    }
    __syncthreads();
    bf16x8 hb[4];
    #pragma unroll
    for (int j = 0; j < 4; j++) hb[j] = *(const bf16x8*)&h1s[wn + j*16 + lr][koff];
    #pragma unroll
    for (int i = 0; i < 8; i++){
      bf16x8 af = *(const bf16x8*)(KA + (wro + i*16 + lr)*256 + k0 + koff);
      #pragma unroll
      for (int j = 0; j < 4; j++)
        acc[i][j] = __builtin_amdgcn_mfma_f32_16x16x32_bf16(af, hb[j], acc[i][j], 0, 0, 0);
    }
    __syncthreads();
  }

  // ---------------- epilogue 1: bias, featS store (swizzled), a_s/a_n partials ----------------
  int c4 = lq * 4;
  float ps[4] = {0.f,0.f,0.f,0.f}, pn[4] = {0.f,0.f,0.f,0.f};
  #pragma unroll
  for (int i = 0; i < 8; i++){
    int ob = wro + i*16 + c4;
    f32x4 bi  = *(const f32x4*)(biases + h*256 + ob);
    f32x4 ws4 = *(const f32x4*)(atts   + h*256 + ob);
    f32x4 wn4 = *(const f32x4*)(attn   + h*256 + ob);
    #pragma unroll
    for (int r = 0; r < 4; r++){
      #pragma unroll
      for (int j = 0; j < 4; j++){
        int nn = wn + j*16 + lr;
        float fv = acc[i][j][r] + bi[r];
        *(short*)(featS + SWZ(ob + r, nn*2)) = f2b(fv);
        ps[j] += fv * ws4[r];
        pn[j] += fv * wn4[r];
      }
    }
  }
  #pragma unroll
  for (int j = 0; j < 4; j++){
    float s = ps[j]; s += __shfl_xor(s, 16); s += __shfl_xor(s, 32);
    float nv = pn[j]; nv += __shfl_xor(nv, 16); nv += __shfl_xor(nv, 32);
    if (lane < 16){
      red_s[w][j*16 + lane] = s;
      red_n[w][j*16 + lane] = nv;
    }
  }
  __syncthreads();
  if (tid < 256){
    int wq = tid >> 6, ln = tid & 63;
    asv[tid] = red_s[wq][ln] + red_s[wq+4][ln] + attb;
    anv[tid] = red_n[wq][ln] + red_n[wq+4][ln];
  }
  __syncthreads();

  // ---------------- phase 2: 8 passes of 32 i-rows ----------------
  for (int it0 = 0; it0 < 256; it0 += 32){
    // phase A: softmax, ALL 512 threads: 16 threads/row x 16 cols
    {
      int row = tid >> 4, seg = tid & 15;
      int i = it0 + row;
      float as_i = asv[i];
      unsigned bits = xbits[(b*256 + i)*8 + (seg >> 1)];
      int sh = (seg & 1) * 16;
      float Lv[16];
      float mx = -3.0e38f;
      #pragma unroll
      for (int e = 0; e < 16; e++){
        float s = as_i + anv[seg*16 + e];
        float el = s > 0.f ? s : (__expf(s) - 1.0f);
        float L = el + (((bits >> (sh + e)) & 1u) ? 0.f : -1.0e10f);
        Lv[e] = L;
        mx = fmaxf(mx, L);
      }
      mx = fmaxf(mx, __shfl_xor(mx, 1));
      mx = fmaxf(mx, __shfl_xor(mx, 2));
      mx = fmaxf(mx, __shfl_xor(mx, 4));
      mx = fmaxf(mx, __shfl_xor(mx, 8));
      float sum = 0.f;
      #pragma unroll
      for (int e = 0; e < 16; e++){ float p = __expf(Lv[e] - mx); Lv[e] = p; sum += p; }
      sum += __shfl_xor(sum, 1);
      sum += __shfl_xor(sum, 2);
      sum += __shfl_xor(sum, 4);
      sum += __shfl_xor(sum, 8);
      float inv = 1.0f / sum;
      #pragma unroll
      for (int q = 0; q < 2; q++){
        bf16x8 pv;
        #pragma unroll
        for (int e = 0; e < 8; e++) pv[e] = f2b(Lv[q*8+e] * inv);
        *(bf16x8*)(Pbuf + SWZ(row, seg*32 + q*16)) = pv;
      }
      if (h == 3){
        float* o2 = out2 + b*65536 + i*256 + seg*16;
        #pragma unroll
        for (int q = 0; q < 4; q++){
          f32x4 v;
          #pragma unroll
          for (int e = 0; e < 4; e++) v[e] = Lv[q*4+e] * inv;
          *(f32x4*)(o2 + q*4) = v;
        }
      }
    }
    __syncthreads();

    // phase B: nodeT tile = P(featS rows, Pbuf) ; wave owns 32 o-rows
    f32x4 acc2[2][2] = {};
    int o0w = w * 32;
    for (int k0 = 0; k0 < 256; k0 += 32){
      bf16x8 af[2], bfr[2];
      #pragma unroll
      for (int ii = 0; ii < 2; ii++)
        af[ii] = *(const bf16x8*)(featS + SWZ(o0w + ii*16 + lr, k0*2 + lq*16));
      #pragma unroll
      for (int jf = 0; jf < 2; jf++)
        bfr[jf] = *(const bf16x8*)(Pbuf + SWZ(jf*16 + lr, k0*2 + lq*16));
      #pragma unroll
      for (int ii = 0; ii < 2; ii++)
        #pragma unroll
        for (int jf = 0; jf < 2; jf++)
          acc2[ii][jf] = __builtin_amdgcn_mfma_f32_16x16x32_bf16(af[ii], bfr[jf], acc2[ii][jf], 0, 0, 0);
    }
    #pragma unroll
    for (int ii = 0; ii < 2; ii++)
      #pragma unroll
      for (int jf = 0; jf < 2; jf++){
        int iW = it0 + jf*16 + lr;
        *(f32x4*)(out + (size_t)(b*256 + iW)*1024 + h*256 + o0w + ii*16 + c4) = acc2[ii][jf];
      }
    __syncthreads();
  }
}

extern "C" void kernel_launch(void* const* d_in, const int* in_sizes, int n_in,
                              void* d_out, int out_size, void* d_ws, size_t ws_size,
                              hipStream_t stream) {
  const float* atom   = (const float*)d_in[0];
  const float* x      = (const float*)d_in[1];
  const float* fc_w   = (const float*)d_in[2];
  const float* fc_b   = (const float*)d_in[3];
  const float* kers   = (const float*)d_in[4];
  const float* att_s  = (const float*)d_in[5];
  const float* att_n  = (const float*)d_in[6];
  const float* eps    = (const float*)d_in[7];
  const float* biases = (const float*)d_in[8];
  const float* att_b  = (const float*)d_in[9];

  // ws layout (~67 MB)
  char* w = (char*)d_ws;
  short* WT      = (short*)(w);                      // 128 KB
  short* KhT     = (short*)(w + 131072);             // 512 KB
  float* diag    = (float*)(w + 655360);             // 128 KB
  unsigned* xbits= (unsigned*)(w + 786432);          // 1 MB
  short* atomG1  = (short*)(w + 1835008);            // 16 MB: atom_bf, then G1
  short* xbf     = (short*)(w + 18612224);           // 16 MB
  short* G2T     = (short*)(w + 35389440);           // 16 MB
  short* G2nf    = (short*)(w + 52166656);           // 16 MB

  float* out  = (float*)d_out;
  float* out2 = out + 33554432;  // B*N*H*D floats

  ktrans<<<dim3(8, 8, 5), 256, 0, stream>>>(fc_w, kers, WT, KhT);
  kprep<<<dim3(8, 128, 2), 256, 0, stream>>>(atom, x, atomG1, xbf, xbits, diag);
  kG2<<<dim3(4, 128), 256, 0, stream>>>(WT, atomG1, G2T, G2nf);
  kG1<<<dim3(4, 128), 256, 0, stream>>>(G2T, xbf, atomG1);   // G1 overwrites atom_bf (dead)

  kHead<<<dim3(512), 512, 0, stream>>>(KhT, atomG1, G2nf, diag, fc_b, eps,
                                       biases, att_s, att_n, xbits, att_b, out, out2);
}